// Round 3
// baseline (47187.839 us; speedup 1.0000x reference)
//
#include <hip/hip_runtime.h>

#define NN 8192
#define DD 32
// stagger-padded LDS index: +4 floats of pad per 16 (keeps 16B alignment)
#define SIDX(c) ((c) + 4 * ((c) >> 4))

constexpr float kEps   = 0.1f;
constexpr float kStab  = 1e-8f;
constexpr float kMass  = 1.0f / 8192.0f;     // mu = nu = 1/n
constexpr float kInvSc = 1.0f / 256.0f;      // K stored as fp8 of 256*K
constexpr float kLnSc  = 5.545177444479562f; // ln(256)

typedef float v2f __attribute__((ext_vector_type(2)));

__device__ inline void cvt8x4(unsigned int w, float* out) {
    v2f lo = __builtin_amdgcn_cvt_pk_f32_fp8(w, false);
    v2f hi = __builtin_amdgcn_cvt_pk_f32_fp8(w, true);
    out[0] = lo.x; out[1] = lo.y; out[2] = hi.x; out[3] = hi.y;
}
__device__ inline void cvt16(uint4 kk, float* f) {
    cvt8x4(kk.x, f); cvt8x4(kk.y, f + 4); cvt8x4(kk.z, f + 8); cvt8x4(kk.w, f + 12);
}
__device__ inline unsigned int pack8x4(float a, float b, float c, float d) {
    int v = 0;
    v = __builtin_amdgcn_cvt_pk_fp8_f32(a, b, v, false);
    v = __builtin_amdgcn_cvt_pk_fp8_f32(c, d, v, true);
    return (unsigned int)v;
}
// dot of 16 fp8 values against 4 float4 v-registers
__device__ inline float dot16(uint4 kk, const float4* v4, float a) {
    float f[16];
    cvt16(kk, f);
    a = fmaf(f[0],  v4[0].x, a); a = fmaf(f[1],  v4[0].y, a);
    a = fmaf(f[2],  v4[0].z, a); a = fmaf(f[3],  v4[0].w, a);
    a = fmaf(f[4],  v4[1].x, a); a = fmaf(f[5],  v4[1].y, a);
    a = fmaf(f[6],  v4[1].z, a); a = fmaf(f[7],  v4[1].w, a);
    a = fmaf(f[8],  v4[2].x, a); a = fmaf(f[9],  v4[2].y, a);
    a = fmaf(f[10], v4[2].z, a); a = fmaf(f[11], v4[2].w, a);
    a = fmaf(f[12], v4[3].x, a); a = fmaf(f[13], v4[3].y, a);
    a = fmaf(f[14], v4[3].z, a); a = fmaf(f[15], v4[3].w, a);
    return a;
}
// c[j] += f8[j] * ur for 16 values
__device__ inline void axpy16(uint4 kk, float ur, float* c) {
    float f[16];
    cvt16(kk, f);
#pragma unroll
    for (int j = 0; j < 16; j++) c[j] = fmaf(f[j], ur, c[j]);
}

// ---------------------------------------------------------------- init u = 1
__global__ void sk_init_u(float* __restrict__ u) {
    u[blockIdx.x * 256 + threadIdx.x] = 1.0f;
}

// -------------------------------- build K8 = fp8(256*exp(-cost/eps)) for one pair
__global__ __launch_bounds__(256) void sk_build_k(const float* __restrict__ X,
                                                  const float* __restrict__ Y,
                                                  unsigned char* __restrict__ K) {
    __shared__ float xs[DD * 64];
    __shared__ float ys[DD * 64];
    __shared__ float sx[64], sy[64];
    const int t  = threadIdx.x;
    const int r0 = blockIdx.y * 64, c0 = blockIdx.x * 64;

    for (int idx = t; idx < DD * 64; idx += 256) {
        int d = idx >> 6, row = idx & 63;
        xs[idx] = X[(size_t)(r0 + row) * DD + d];
        ys[idx] = Y[(size_t)(c0 + row) * DD + d];
    }
    __syncthreads();
    if (t < 64) {
        float s = 0.f;
        for (int d = 0; d < DD; d++) { float v = xs[d * 64 + t]; s = fmaf(v, v, s); }
        sx[t] = s;
    } else if (t < 128) {
        int q = t - 64; float s = 0.f;
        for (int d = 0; d < DD; d++) { float v = ys[d * 64 + q]; s = fmaf(v, v, s); }
        sy[q] = s;
    }
    __syncthreads();

    const int tr = t >> 4, tc = t & 15;
    float acc[4][4] = {};
    for (int d = 0; d < DD; d++) {
        const float4 xa = *reinterpret_cast<const float4*>(&xs[d * 64 + 4 * tr]);
        const float4 yb = *reinterpret_cast<const float4*>(&ys[d * 64 + 4 * tc]);
        const float xav[4] = {xa.x, xa.y, xa.z, xa.w};
        const float ybv[4] = {yb.x, yb.y, yb.z, yb.w};
#pragma unroll
        for (int a = 0; a < 4; a++)
#pragma unroll
            for (int b = 0; b < 4; b++) acc[a][b] = fmaf(xav[a], ybv[b], acc[a][b]);
    }
#pragma unroll
    for (int a = 0; a < 4; a++) {
        const int r = r0 + 4 * tr + a;
        const float sxa = sx[4 * tr + a];
        float e[4];
#pragma unroll
        for (int b = 0; b < 4; b++) {
            float cost = sxa + sy[4 * tc + b] - 2.0f * acc[a][b];
            cost = fmaxf(cost, 0.0f);
            e[b] = expf(fmaf(-10.0f, cost, kLnSc));   // 256 * exp(-cost/eps)
        }
        *reinterpret_cast<unsigned int*>(&K[(size_t)r * NN + c0 + 4 * tc]) =
            pack8x4(e[0], e[1], e[2], e[3]);
    }
}

// -------------------------------- initial column sums: rc[z] += K[z]^T u[z] (u = 1)
// one-shot, 64 contenders/address — benign atomic regime (round-0 evidence).
__global__ __launch_bounds__(256) void sk_colsum(const unsigned char* __restrict__ K8,
                                                 const float* __restrict__ u,
                                                 float* __restrict__ rc_out) {
    __shared__ float us[128];
    __shared__ float red[4 * 1280];   // 4 waves x staggered 1024
    const int t = threadIdx.x, lane = t & 63, w = t >> 6;
    const int z = blockIdx.z;
    const int c0 = blockIdx.x * 1024, r0 = blockIdx.y * 128;
    const unsigned char* K = K8 + (size_t)z * NN * NN;
    if (t < 128) us[t] = u[z * NN + r0 + t];
    __syncthreads();

    float acc[16] = {};
    const unsigned char* p = K + (size_t)(r0 + 32 * w) * NN + c0 + 16 * lane;
    for (int i = 0; i < 32; i += 4) {
        uint4 k0 = *reinterpret_cast<const uint4*>(p);
        uint4 k1 = *reinterpret_cast<const uint4*>(p + (size_t)NN);
        uint4 k2 = *reinterpret_cast<const uint4*>(p + (size_t)2 * NN);
        uint4 k3 = *reinterpret_cast<const uint4*>(p + (size_t)3 * NN);
        p += (size_t)4 * NN;
        const float u0 = us[32 * w + i + 0], u1 = us[32 * w + i + 1];
        const float u2 = us[32 * w + i + 2], u3 = us[32 * w + i + 3];
        float f[16];
        cvt16(k0, f);
#pragma unroll
        for (int j = 0; j < 16; j++) acc[j] = fmaf(f[j], u0, acc[j]);
        cvt16(k1, f);
#pragma unroll
        for (int j = 0; j < 16; j++) acc[j] = fmaf(f[j], u1, acc[j]);
        cvt16(k2, f);
#pragma unroll
        for (int j = 0; j < 16; j++) acc[j] = fmaf(f[j], u2, acc[j]);
        cvt16(k3, f);
#pragma unroll
        for (int j = 0; j < 16; j++) acc[j] = fmaf(f[j], u3, acc[j]);
    }
    float* rw = &red[w * 1280 + 20 * lane];   // SIDX(16*lane) = 20*lane
#pragma unroll
    for (int g = 0; g < 4; g++) {
        float4 v = {acc[4 * g + 0], acc[4 * g + 1], acc[4 * g + 2], acc[4 * g + 3]};
        *reinterpret_cast<float4*>(rw + 4 * g) = v;
    }
    __syncthreads();
    for (int c = t; c < 1024; c += 256) {
        const int sc = SIDX(c);
        const float s = red[sc] + red[1280 + sc] + red[2560 + sc] + red[3840 + sc];
        atomicAdd(&rc_out[z * NN + c0 + c], s);
    }
}

// -------------------------------- v[c] = m / (raw[c]/256 + stab)  (once, after colsum)
__global__ void sk_v(const float* __restrict__ rc, float* __restrict__ v) {
    const int i = (blockIdx.z * gridDim.x + blockIdx.x) * 256 + threadIdx.x;
    v[i] = kMass * __builtin_amdgcn_rcpf(fmaf(rc[i], kInvSc, kStab));
}

// -------------------------------- fused iteration, register-resident K panels:
// Block owns 32 rows x 8192 cols. Wave w owns col strip [2048w, 2048w+2048);
// lane owns 32 fixed cols (16 at c0+16*lane, 16 at c0+1024+16*lane) for ALL rows.
// v for those cols lives in registers (loaded from v_in). Per 8-row group: packed
// fp8 K held in 64 VGPRs, used for row sums (-> u_new via cross-wave LDS reduce)
// then re-converted in-register for column partials. K read from HBM exactly once.
// Column partials are stored NON-ATOMICALLY to rcp[z][bid][8192] (no contention).
__global__ __launch_bounds__(256, 3) void sk_iter(const unsigned char* __restrict__ K8,
                                                  const float* __restrict__ v_in,
                                                  float* __restrict__ rcp,
                                                  float* __restrict__ u_out,
                                                  int last) {
    __shared__ float cs[10240];        // staggered 8192: colsum drain buffer
    __shared__ float red[4][4][8];     // group x wave x row partial rowsums
    const int t = threadIdx.x, lane = t & 63, w = t >> 6;
    const int z = blockIdx.z;
    const unsigned char* K = K8 + (size_t)z * NN * NN;
    const int rowbase = blockIdx.x * 32;
    const int c0 = 2048 * w;

    // ---- v for this lane's 32 columns, in registers
    float4 vv[8];
    {
        const float* vz = v_in + (size_t)z * NN + c0 + 16 * lane;
#pragma unroll
        for (int i = 0; i < 4; i++) vv[i] = reinterpret_cast<const float4*>(vz)[i];
#pragma unroll
        for (int i = 0; i < 4; i++) vv[4 + i] = reinterpret_cast<const float4*>(vz + 1024)[i];
    }

    float cacc[32] = {};
#pragma unroll
    for (int g = 0; g < 4; g++) {
        const int rb = rowbase + 8 * g;
        // load 8 rows of packed fp8 (this lane's 32 cols) into registers
        uint4 kr0[8], kr1[8];
        {
            const unsigned char* kp = K + (size_t)rb * NN + c0 + 16 * lane;
#pragma unroll
            for (int r = 0; r < 8; r++) {
                kr0[r] = *reinterpret_cast<const uint4*>(kp);
                kr1[r] = *reinterpret_cast<const uint4*>(kp + 1024);
                kp += NN;
            }
        }
        // phase 1: per-lane partial row sums -> wave reduce -> LDS
#pragma unroll
        for (int r = 0; r < 8; r++) {
            float p = dot16(kr0[r], &vv[0], 0.0f);
            p = dot16(kr1[r], &vv[4], p);
            for (int off = 32; off > 0; off >>= 1) p += __shfl_down(p, off);
            if (lane == 0) red[g][w][r] = p;
        }
        __syncthreads();
        // every wave computes u for the 8 rows (identical fp math, no 2nd sync)
        float ug[8];
#pragma unroll
        for (int r = 0; r < 8; r++) {
            const float s = red[g][0][r] + red[g][1][r] + red[g][2][r] + red[g][3][r];
            ug[r] = kMass / (s * kInvSc + kStab);
            if (w == 0 && lane == r) u_out[(size_t)z * NN + rb + r] = ug[r];
        }
        // phase 2: re-convert the SAME registers, accumulate column partials
#pragma unroll
        for (int r = 0; r < 8; r++) {
            axpy16(kr0[r], ug[r], &cacc[0]);
            axpy16(kr1[r], ug[r], &cacc[16]);
        }
    }
    if (last) return;   // uniform: final iteration needs no next colsum

    // ---- drain: stage strip partials in LDS, then plain coalesced stores
    {
        float* b0 = &cs[SIDX(c0 + 16 * lane)];          // base%16==0 -> SIDX(+j)=SIDX+j
        float* b1 = &cs[SIDX(c0 + 1024 + 16 * lane)];
#pragma unroll
        for (int q = 0; q < 4; q++) {
            float4 v4 = {cacc[4 * q + 0], cacc[4 * q + 1], cacc[4 * q + 2], cacc[4 * q + 3]};
            *reinterpret_cast<float4*>(b0 + 4 * q) = v4;
        }
#pragma unroll
        for (int q = 0; q < 4; q++) {
            float4 v4 = {cacc[16 + 4 * q + 0], cacc[16 + 4 * q + 1],
                         cacc[16 + 4 * q + 2], cacc[16 + 4 * q + 3]};
            *reinterpret_cast<float4*>(b1 + 4 * q) = v4;
        }
    }
    __syncthreads();
    float* rp = rcp + ((size_t)z * 256 + blockIdx.x) * NN;
    for (int i = 4 * t; i < NN; i += 1024) {             // 8 x float4 per thread
        float4 v4 = *reinterpret_cast<const float4*>(&cs[SIDX(i)]);
        *reinterpret_cast<float4*>(&rp[i]) = v4;
    }
}

// -------------------------------- fold 256 block partials -> v (next iteration)
// grid (128, 1, nb), 256 threads: block owns 64 cols; thread quarter-sums 64 rows.
__global__ __launch_bounds__(256) void sk_reduce(const float* __restrict__ rcp,
                                                 float* __restrict__ v_out) {
    __shared__ float sred[4][64];
    const int t = threadIdx.x, tc = t & 63, tq = t >> 6;
    const int z = blockIdx.z;
    const int c = blockIdx.x * 64 + tc;
    const float* base = rcp + (size_t)z * 256 * NN + c;
    float acc = 0.f;
#pragma unroll 8
    for (int r = tq * 64; r < tq * 64 + 64; r++) acc += base[(size_t)r * NN];
    sred[tq][tc] = acc;
    __syncthreads();
    if (t < 64) {
        const float s = sred[0][t] + sred[1][t] + sred[2][t] + sred[3][t];
        v_out[(size_t)z * NN + blockIdx.x * 64 + t] =
            kMass * __builtin_amdgcn_rcpf(fmaf(s, kInvSc, kStab));
    }
}

// -------------------------------- w[z] = sum u_i K_ij v_j cost_ij, cost = -eps*ln(K)
__global__ __launch_bounds__(256) void sk_wsum(const unsigned char* __restrict__ K8,
                                               const float* __restrict__ v_in,
                                               const float* __restrict__ u,
                                               double* __restrict__ acc_out) {
    __shared__ float vs[10240];
    __shared__ double wred[4];
    const int t = threadIdx.x;
    const int z = blockIdx.z;
    const unsigned char* K = K8 + (size_t)z * NN * NN;
    const float* v = v_in + (size_t)z * NN;
#pragma unroll
    for (int q = 0; q < 8; q++) {
        const int j = 4 * t + 1024 * q;
        *reinterpret_cast<float4*>(&vs[SIDX(j)]) = *reinterpret_cast<const float4*>(v + j);
    }
    __syncthreads();

    const int lane = t & 63, w = t >> 6;
    const int rbase = blockIdx.x * 32 + 8 * w;
    float pr[8] = {};
    const unsigned char* rp = K + (size_t)rbase * NN + 16 * lane;
    for (int s = 0; s < 8; s++) {
        const float* vp = &vs[20 * lane + 1280 * s];
        float vv[16];
#pragma unroll
        for (int g = 0; g < 4; g++) {
            float4 v4 = *reinterpret_cast<const float4*>(vp + 4 * g);
            vv[4 * g] = v4.x; vv[4 * g + 1] = v4.y; vv[4 * g + 2] = v4.z; vv[4 * g + 3] = v4.w;
        }
        const unsigned char* ps = rp + 1024 * s;
#pragma unroll
        for (int r = 0; r < 8; r++) {
            uint4 kk = *reinterpret_cast<const uint4*>(ps + (size_t)r * NN);
            float f[16];
            cvt16(kk, f);
            float a = pr[r];
#pragma unroll
            for (int j = 0; j < 16; j++) {
                // term k*v*ln(k): zero when f==0 since f*v==0
                a = fmaf(f[j] * vv[j], __logf(fmaxf(f[j], 1e-30f) * kInvSc), a);
            }
            pr[r] = a;
        }
    }
    double lacc = 0.0;
#pragma unroll
    for (int r = 0; r < 8; r++)
        lacc += (double)(u[(size_t)z * NN + rbase + r] * pr[r]);
    lacc *= (double)kInvSc;
    for (int off = 32; off > 0; off >>= 1) lacc += __shfl_down(lacc, off);
    if (lane == 0) wred[w] = lacc;
    __syncthreads();
    if (t == 0) {
        double total = -(double)kEps * (wred[0] + wred[1] + wred[2] + wred[3]);
        atomicAdd(&acc_out[z], total);
    }
}

// ------------------------------------------------- combine
__global__ void sk_combine(const double* __restrict__ acc, float* __restrict__ out) {
    if (threadIdx.x == 0)
        out[0] = (float)((acc[0] - 0.5 * acc[1] - 0.5 * acc[2]) / 8192.0);
}

extern "C" void kernel_launch(void* const* d_in, const int* in_sizes, int n_in,
                              void* d_out, int out_size, void* d_ws, size_t ws_size,
                              hipStream_t stream) {
    const float* src = (const float*)d_in[0];
    const float* tgt = (const float*)d_in[1];
    float* out = (float*)d_out;
    char* ws = (char*)d_ws;

    // batched needs: 3 K matrices + 3x256x8192 partials + vectors
    const size_t need3 = 3ull * NN * NN + 3ull * 256 * NN * 4 + 16ull * NN * 4 + 1024;
    const bool batched = ws_size >= need3;
    const int B = batched ? 3 : 1;

    unsigned char* K8 = (unsigned char*)ws;
    float*  rcp  = (float*)(ws + (size_t)B * NN * NN);
    float*  vb   = rcp + (size_t)B * 256 * NN;
    float*  u    = vb + (size_t)B * NN;
    float*  rc0  = u + (size_t)B * NN;
    double* wacc = (double*)(rc0 + (size_t)B * NN);

    hipMemsetAsync(wacc, 0, 3 * sizeof(double), stream);
    const float* pts[3][2] = {{src, tgt}, {src, src}, {tgt, tgt}};

    if (batched) {
        hipMemsetAsync(rc0, 0, 3ull * NN * sizeof(float), stream);
        sk_init_u<<<3 * NN / 256, 256, 0, stream>>>(u);
        for (int i = 0; i < 3; i++)
            sk_build_k<<<dim3(128, 128, 1), 256, 0, stream>>>(pts[i][0], pts[i][1],
                                                              K8 + (size_t)i * NN * NN);
        sk_colsum<<<dim3(8, 64, 3), 256, 0, stream>>>(K8, u, rc0);   // raw K^T 1
        sk_v<<<dim3(32, 1, 3), 256, 0, stream>>>(rc0, vb);           // v_1
        for (int t = 1; t <= 100; t++) {
            sk_iter<<<dim3(256, 1, 3), 256, 0, stream>>>(K8, vb, rcp, u, t == 100 ? 1 : 0);
            if (t < 100)
                sk_reduce<<<dim3(128, 1, 3), 256, 0, stream>>>(rcp, vb);
        }
        // after t=100: u = u_100, vb = v_100
        sk_wsum<<<dim3(256, 1, 3), 256, 0, stream>>>(K8, vb, u, wacc);
    } else {
        for (int tf = 0; tf < 3; tf++) {
            hipMemsetAsync(rc0, 0, 1ull * NN * sizeof(float), stream);
            sk_init_u<<<NN / 256, 256, 0, stream>>>(u);
            sk_build_k<<<dim3(128, 128, 1), 256, 0, stream>>>(pts[tf][0], pts[tf][1], K8);
            sk_colsum<<<dim3(8, 64, 1), 256, 0, stream>>>(K8, u, rc0);
            sk_v<<<dim3(32, 1, 1), 256, 0, stream>>>(rc0, vb);
            for (int t = 1; t <= 100; t++) {
                sk_iter<<<dim3(256, 1, 1), 256, 0, stream>>>(K8, vb, rcp, u, t == 100 ? 1 : 0);
                if (t < 100)
                    sk_reduce<<<dim3(128, 1, 1), 256, 0, stream>>>(rcp, vb);
            }
            sk_wsum<<<dim3(256, 1, 1), 256, 0, stream>>>(K8, vb, u, &wacc[tf]);
        }
    }
    sk_combine<<<1, 64, 0, stream>>>(wacc, out);
}

// Round 4
// 40670.108 us; speedup vs baseline: 1.1603x; 1.1603x over previous
//
#include <hip/hip_runtime.h>

#define NN 8192
#define DD 32
// stagger-padded LDS index: +4 floats of pad per 16 (keeps 16B alignment)
#define SIDX(c) ((c) + 4 * ((c) >> 4))

constexpr float kEps   = 0.1f;
constexpr float kStab  = 1e-8f;
constexpr float kMass  = 1.0f / 8192.0f;     // mu = nu = 1/n
constexpr float kInvSc = 1.0f / 256.0f;      // K stored as fp8 of 256*K
constexpr float kLnSc  = 5.545177444479562f; // ln(256)

typedef float v2f __attribute__((ext_vector_type(2)));

__device__ inline void cvt8x4(unsigned int w, float* out) {
    v2f lo = __builtin_amdgcn_cvt_pk_f32_fp8(w, false);
    v2f hi = __builtin_amdgcn_cvt_pk_f32_fp8(w, true);
    out[0] = lo.x; out[1] = lo.y; out[2] = hi.x; out[3] = hi.y;
}
__device__ inline void cvt16(uint4 kk, float* f) {
    cvt8x4(kk.x, f); cvt8x4(kk.y, f + 4); cvt8x4(kk.z, f + 8); cvt8x4(kk.w, f + 12);
}
__device__ inline unsigned int pack8x4(float a, float b, float c, float d) {
    int v = 0;
    v = __builtin_amdgcn_cvt_pk_fp8_f32(a, b, v, false);
    v = __builtin_amdgcn_cvt_pk_fp8_f32(c, d, v, true);
    return (unsigned int)v;
}
// dot of 16 fp8 values against v (by-value float4s -> SROA-friendly)
__device__ inline float dot16v(uint4 kk, float4 a, float4 b, float4 c, float4 d) {
    float f[16];
    cvt16(kk, f);
    float s = 0.f;
    s = fmaf(f[0],  a.x, s); s = fmaf(f[1],  a.y, s);
    s = fmaf(f[2],  a.z, s); s = fmaf(f[3],  a.w, s);
    s = fmaf(f[4],  b.x, s); s = fmaf(f[5],  b.y, s);
    s = fmaf(f[6],  b.z, s); s = fmaf(f[7],  b.w, s);
    s = fmaf(f[8],  c.x, s); s = fmaf(f[9],  c.y, s);
    s = fmaf(f[10], c.z, s); s = fmaf(f[11], c.w, s);
    s = fmaf(f[12], d.x, s); s = fmaf(f[13], d.y, s);
    s = fmaf(f[14], d.z, s); s = fmaf(f[15], d.w, s);
    return s;
}
// col-acc += f8 * ur, accumulators as float4 refs (SROA-friendly)
__device__ inline void axpy16v(uint4 kk, float ur,
                               float4& c0, float4& c1, float4& c2, float4& c3) {
    float f[16];
    cvt16(kk, f);
    c0.x = fmaf(f[0],  ur, c0.x); c0.y = fmaf(f[1],  ur, c0.y);
    c0.z = fmaf(f[2],  ur, c0.z); c0.w = fmaf(f[3],  ur, c0.w);
    c1.x = fmaf(f[4],  ur, c1.x); c1.y = fmaf(f[5],  ur, c1.y);
    c1.z = fmaf(f[6],  ur, c1.z); c1.w = fmaf(f[7],  ur, c1.w);
    c2.x = fmaf(f[8],  ur, c2.x); c2.y = fmaf(f[9],  ur, c2.y);
    c2.z = fmaf(f[10], ur, c2.z); c2.w = fmaf(f[11], ur, c2.w);
    c3.x = fmaf(f[12], ur, c3.x); c3.y = fmaf(f[13], ur, c3.y);
    c3.z = fmaf(f[14], ur, c3.z); c3.w = fmaf(f[15], ur, c3.w);
}

// ---------------------------------------------------------------- init u = 1
__global__ void sk_init_u(float* __restrict__ u) {
    u[blockIdx.x * 256 + threadIdx.x] = 1.0f;
}

// -------------------------------- build K8 = fp8(256*exp(-cost/eps)) for one pair
__global__ __launch_bounds__(256) void sk_build_k(const float* __restrict__ X,
                                                  const float* __restrict__ Y,
                                                  unsigned char* __restrict__ K) {
    __shared__ float xs[DD * 64];
    __shared__ float ys[DD * 64];
    __shared__ float sx[64], sy[64];
    const int t  = threadIdx.x;
    const int r0 = blockIdx.y * 64, c0 = blockIdx.x * 64;

    for (int idx = t; idx < DD * 64; idx += 256) {
        int d = idx >> 6, row = idx & 63;
        xs[idx] = X[(size_t)(r0 + row) * DD + d];
        ys[idx] = Y[(size_t)(c0 + row) * DD + d];
    }
    __syncthreads();
    if (t < 64) {
        float s = 0.f;
        for (int d = 0; d < DD; d++) { float v = xs[d * 64 + t]; s = fmaf(v, v, s); }
        sx[t] = s;
    } else if (t < 128) {
        int q = t - 64; float s = 0.f;
        for (int d = 0; d < DD; d++) { float v = ys[d * 64 + q]; s = fmaf(v, v, s); }
        sy[q] = s;
    }
    __syncthreads();

    const int tr = t >> 4, tc = t & 15;
    float acc[4][4] = {};
    for (int d = 0; d < DD; d++) {
        const float4 xa = *reinterpret_cast<const float4*>(&xs[d * 64 + 4 * tr]);
        const float4 yb = *reinterpret_cast<const float4*>(&ys[d * 64 + 4 * tc]);
        const float xav[4] = {xa.x, xa.y, xa.z, xa.w};
        const float ybv[4] = {yb.x, yb.y, yb.z, yb.w};
#pragma unroll
        for (int a = 0; a < 4; a++)
#pragma unroll
            for (int b = 0; b < 4; b++) acc[a][b] = fmaf(xav[a], ybv[b], acc[a][b]);
    }
#pragma unroll
    for (int a = 0; a < 4; a++) {
        const int r = r0 + 4 * tr + a;
        const float sxa = sx[4 * tr + a];
        float e[4];
#pragma unroll
        for (int b = 0; b < 4; b++) {
            float cost = sxa + sy[4 * tc + b] - 2.0f * acc[a][b];
            cost = fmaxf(cost, 0.0f);
            e[b] = expf(fmaf(-10.0f, cost, kLnSc));   // 256 * exp(-cost/eps)
        }
        *reinterpret_cast<unsigned int*>(&K[(size_t)r * NN + c0 + 4 * tc]) =
            pack8x4(e[0], e[1], e[2], e[3]);
    }
}

// -------------------------------- initial column sums: rc[z] += K[z]^T u[z] (u = 1)
// one-shot, 64 contenders/address — benign atomic regime (round-0 evidence).
__global__ __launch_bounds__(256) void sk_colsum(const unsigned char* __restrict__ K8,
                                                 const float* __restrict__ u,
                                                 float* __restrict__ rc_out) {
    __shared__ float us[128];
    __shared__ float red[4 * 1280];   // 4 waves x staggered 1024
    const int t = threadIdx.x, lane = t & 63, w = t >> 6;
    const int z = blockIdx.z;
    const int c0 = blockIdx.x * 1024, r0 = blockIdx.y * 128;
    const unsigned char* K = K8 + (size_t)z * NN * NN;
    if (t < 128) us[t] = u[z * NN + r0 + t];
    __syncthreads();

    float acc[16] = {};
    const unsigned char* p = K + (size_t)(r0 + 32 * w) * NN + c0 + 16 * lane;
    for (int i = 0; i < 32; i += 4) {
        uint4 k0 = *reinterpret_cast<const uint4*>(p);
        uint4 k1 = *reinterpret_cast<const uint4*>(p + (size_t)NN);
        uint4 k2 = *reinterpret_cast<const uint4*>(p + (size_t)2 * NN);
        uint4 k3 = *reinterpret_cast<const uint4*>(p + (size_t)3 * NN);
        p += (size_t)4 * NN;
        const float u0 = us[32 * w + i + 0], u1 = us[32 * w + i + 1];
        const float u2 = us[32 * w + i + 2], u3 = us[32 * w + i + 3];
        float f[16];
        cvt16(k0, f);
#pragma unroll
        for (int j = 0; j < 16; j++) acc[j] = fmaf(f[j], u0, acc[j]);
        cvt16(k1, f);
#pragma unroll
        for (int j = 0; j < 16; j++) acc[j] = fmaf(f[j], u1, acc[j]);
        cvt16(k2, f);
#pragma unroll
        for (int j = 0; j < 16; j++) acc[j] = fmaf(f[j], u2, acc[j]);
        cvt16(k3, f);
#pragma unroll
        for (int j = 0; j < 16; j++) acc[j] = fmaf(f[j], u3, acc[j]);
    }
    float* rw = &red[w * 1280 + 20 * lane];   // SIDX(16*lane) = 20*lane
#pragma unroll
    for (int g = 0; g < 4; g++) {
        float4 v = {acc[4 * g + 0], acc[4 * g + 1], acc[4 * g + 2], acc[4 * g + 3]};
        *reinterpret_cast<float4*>(rw + 4 * g) = v;
    }
    __syncthreads();
    for (int c = t; c < 1024; c += 256) {
        const int sc = SIDX(c);
        const float s = red[sc] + red[1280 + sc] + red[2560 + sc] + red[3840 + sc];
        atomicAdd(&rc_out[z * NN + c0 + c], s);
    }
}

// -------------------------------- v[c] = m / (raw[c]/256 + stab)  (once, after colsum)
__global__ void sk_v(const float* __restrict__ rc, float* __restrict__ v) {
    const int i = (blockIdx.z * gridDim.x + blockIdx.x) * 256 + threadIdx.x;
    v[i] = kMass * __builtin_amdgcn_rcpf(fmaf(rc[i], kInvSc, kStab));
}

// -------------------------------- fused iteration, register-resident K, low-pressure:
// 512 threads = 8 waves. Block owns 32 rows x 8192 cols. Wave w owns col strip
// [1024w, 1024w+1024); lane owns 16 fixed cols (one uint4/row) for ALL rows.
// Per 4-row group: 4 uint4 of K in registers, used for row sums (-> u via
// cross-wave LDS reduce) then re-converted in-register for column partials.
// Per-lane live state ~50 VGPR (v 16 + K 16 + acc 16) -> no scratch spill.
// K is read from HBM exactly once; col partials stored non-atomically to
// rcp[z][bid][8192].
__global__ __launch_bounds__(512, 2) void sk_iter(const unsigned char* __restrict__ K8,
                                                  const float* __restrict__ v_in,
                                                  float* __restrict__ rcp,
                                                  float* __restrict__ u_out,
                                                  int last) {
    __shared__ float cs[10240];        // staggered 8192: colsum drain buffer
    __shared__ float red[8][8][4];     // group x wave x row partial rowsums
    const int t = threadIdx.x, lane = t & 63, w = t >> 6;
    const int z = blockIdx.z;
    const unsigned char* K = K8 + (size_t)z * NN * NN;
    const int rowbase = blockIdx.x * 32;
    const int c0 = 1024 * w;

    // ---- v for this lane's 16 columns, in registers
    float4 va, vb, vc, vd;
    {
        const float* vz = v_in + (size_t)z * NN + c0 + 16 * lane;
        va = reinterpret_cast<const float4*>(vz)[0];
        vb = reinterpret_cast<const float4*>(vz)[1];
        vc = reinterpret_cast<const float4*>(vz)[2];
        vd = reinterpret_cast<const float4*>(vz)[3];
    }

    float4 ca0 = {0,0,0,0}, ca1 = {0,0,0,0}, ca2 = {0,0,0,0}, ca3 = {0,0,0,0};
#pragma unroll
    for (int g = 0; g < 8; g++) {
        const int rb = rowbase + 4 * g;
        // load 4 rows of packed fp8 (this lane's 16 cols) into registers
        uint4 k0, k1, k2, k3;
        {
            const unsigned char* kp = K + (size_t)rb * NN + c0 + 16 * lane;
            k0 = *reinterpret_cast<const uint4*>(kp);
            k1 = *reinterpret_cast<const uint4*>(kp + (size_t)NN);
            k2 = *reinterpret_cast<const uint4*>(kp + (size_t)2 * NN);
            k3 = *reinterpret_cast<const uint4*>(kp + (size_t)3 * NN);
        }
        // phase 1: per-lane partial row sums -> wave reduce -> LDS
        float p0 = dot16v(k0, va, vb, vc, vd);
        float p1 = dot16v(k1, va, vb, vc, vd);
        float p2 = dot16v(k2, va, vb, vc, vd);
        float p3 = dot16v(k3, va, vb, vc, vd);
#pragma unroll
        for (int off = 32; off > 0; off >>= 1) {
            p0 += __shfl_down(p0, off);
            p1 += __shfl_down(p1, off);
            p2 += __shfl_down(p2, off);
            p3 += __shfl_down(p3, off);
        }
        if (lane == 0) {
            red[g][w][0] = p0; red[g][w][1] = p1;
            red[g][w][2] = p2; red[g][w][3] = p3;
        }
        __syncthreads();
        // every wave computes u for the 4 rows (identical fp math, no 2nd sync)
        float ug[4];
#pragma unroll
        for (int r = 0; r < 4; r++) {
            float s = 0.f;
#pragma unroll
            for (int ww = 0; ww < 8; ww++) s += red[g][ww][r];
            ug[r] = kMass / (s * kInvSc + kStab);
            if (w == 0 && lane == r) u_out[(size_t)z * NN + rb + r] = ug[r];
        }
        // phase 2: re-convert the SAME registers, accumulate column partials
        axpy16v(k0, ug[0], ca0, ca1, ca2, ca3);
        axpy16v(k1, ug[1], ca0, ca1, ca2, ca3);
        axpy16v(k2, ug[2], ca0, ca1, ca2, ca3);
        axpy16v(k3, ug[3], ca0, ca1, ca2, ca3);
    }
    if (last) return;   // uniform: final iteration needs no next colsum

    // ---- drain: stage strip partials in LDS, then plain coalesced stores
    {
        float* b0 = &cs[SIDX(c0 + 16 * lane)];   // base%16==0 -> SIDX(base+j)=SIDX(base)+j
        *reinterpret_cast<float4*>(b0 + 0)  = ca0;
        *reinterpret_cast<float4*>(b0 + 4)  = ca1;
        *reinterpret_cast<float4*>(b0 + 8)  = ca2;
        *reinterpret_cast<float4*>(b0 + 12) = ca3;
    }
    __syncthreads();
    float* rp = rcp + ((size_t)z * 256 + blockIdx.x) * NN;
    for (int i = 4 * t; i < NN; i += 2048) {             // 4 x float4 per thread
        float4 v4 = *reinterpret_cast<const float4*>(&cs[SIDX(i)]);
        *reinterpret_cast<float4*>(&rp[i]) = v4;
    }
}

// -------------------------------- fold 256 block partials -> v (next iteration)
// grid (128, 1, nb), 256 threads: block owns 64 cols; thread quarter-sums 64 rows.
__global__ __launch_bounds__(256) void sk_reduce(const float* __restrict__ rcp,
                                                 float* __restrict__ v_out) {
    __shared__ float sred[4][64];
    const int t = threadIdx.x, tc = t & 63, tq = t >> 6;
    const int z = blockIdx.z;
    const int c = blockIdx.x * 64 + tc;
    const float* base = rcp + (size_t)z * 256 * NN + c;
    float acc = 0.f;
#pragma unroll 8
    for (int r = tq * 64; r < tq * 64 + 64; r++) acc += base[(size_t)r * NN];
    sred[tq][tc] = acc;
    __syncthreads();
    if (t < 64) {
        const float s = sred[0][t] + sred[1][t] + sred[2][t] + sred[3][t];
        v_out[(size_t)z * NN + blockIdx.x * 64 + t] =
            kMass * __builtin_amdgcn_rcpf(fmaf(s, kInvSc, kStab));
    }
}

// -------------------------------- w[z] = sum u_i K_ij v_j cost_ij, cost = -eps*ln(K)
__global__ __launch_bounds__(256) void sk_wsum(const unsigned char* __restrict__ K8,
                                               const float* __restrict__ v_in,
                                               const float* __restrict__ u,
                                               double* __restrict__ acc_out) {
    __shared__ float vs[10240];
    __shared__ double wred[4];
    const int t = threadIdx.x;
    const int z = blockIdx.z;
    const unsigned char* K = K8 + (size_t)z * NN * NN;
    const float* v = v_in + (size_t)z * NN;
#pragma unroll
    for (int q = 0; q < 8; q++) {
        const int j = 4 * t + 1024 * q;
        *reinterpret_cast<float4*>(&vs[SIDX(j)]) = *reinterpret_cast<const float4*>(v + j);
    }
    __syncthreads();

    const int lane = t & 63, w = t >> 6;
    const int rbase = blockIdx.x * 32 + 8 * w;
    float pr[8] = {};
    const unsigned char* rp = K + (size_t)rbase * NN + 16 * lane;
    for (int s = 0; s < 8; s++) {
        const float* vp = &vs[20 * lane + 1280 * s];
        float vv[16];
#pragma unroll
        for (int g = 0; g < 4; g++) {
            float4 v4 = *reinterpret_cast<const float4*>(vp + 4 * g);
            vv[4 * g] = v4.x; vv[4 * g + 1] = v4.y; vv[4 * g + 2] = v4.z; vv[4 * g + 3] = v4.w;
        }
        const unsigned char* ps = rp + 1024 * s;
#pragma unroll
        for (int r = 0; r < 8; r++) {
            uint4 kk = *reinterpret_cast<const uint4*>(ps + (size_t)r * NN);
            float f[16];
            cvt16(kk, f);
            float a = pr[r];
#pragma unroll
            for (int j = 0; j < 16; j++) {
                // term k*v*ln(k): zero when f==0 since f*v==0
                a = fmaf(f[j] * vv[j], __logf(fmaxf(f[j], 1e-30f) * kInvSc), a);
            }
            pr[r] = a;
        }
    }
    double lacc = 0.0;
#pragma unroll
    for (int r = 0; r < 8; r++)
        lacc += (double)(u[(size_t)z * NN + rbase + r] * pr[r]);
    lacc *= (double)kInvSc;
    for (int off = 32; off > 0; off >>= 1) lacc += __shfl_down(lacc, off);
    if (lane == 0) wred[w] = lacc;
    __syncthreads();
    if (t == 0) {
        double total = -(double)kEps * (wred[0] + wred[1] + wred[2] + wred[3]);
        atomicAdd(&acc_out[z], total);
    }
}

// ------------------------------------------------- combine
__global__ void sk_combine(const double* __restrict__ acc, float* __restrict__ out) {
    if (threadIdx.x == 0)
        out[0] = (float)((acc[0] - 0.5 * acc[1] - 0.5 * acc[2]) / 8192.0);
}

extern "C" void kernel_launch(void* const* d_in, const int* in_sizes, int n_in,
                              void* d_out, int out_size, void* d_ws, size_t ws_size,
                              hipStream_t stream) {
    const float* src = (const float*)d_in[0];
    const float* tgt = (const float*)d_in[1];
    float* out = (float*)d_out;
    char* ws = (char*)d_ws;

    // batched needs: 3 K matrices + 3x256x8192 partials + vectors
    const size_t need3 = 3ull * NN * NN + 3ull * 256 * NN * 4 + 16ull * NN * 4 + 1024;
    const bool batched = ws_size >= need3;
    const int B = batched ? 3 : 1;

    unsigned char* K8 = (unsigned char*)ws;
    float*  rcp  = (float*)(ws + (size_t)B * NN * NN);
    float*  vb   = rcp + (size_t)B * 256 * NN;
    float*  u    = vb + (size_t)B * NN;
    float*  rc0  = u + (size_t)B * NN;
    double* wacc = (double*)(rc0 + (size_t)B * NN);

    hipMemsetAsync(wacc, 0, 3 * sizeof(double), stream);
    const float* pts[3][2] = {{src, tgt}, {src, src}, {tgt, tgt}};

    if (batched) {
        hipMemsetAsync(rc0, 0, 3ull * NN * sizeof(float), stream);
        sk_init_u<<<3 * NN / 256, 256, 0, stream>>>(u);
        for (int i = 0; i < 3; i++)
            sk_build_k<<<dim3(128, 128, 1), 256, 0, stream>>>(pts[i][0], pts[i][1],
                                                              K8 + (size_t)i * NN * NN);
        sk_colsum<<<dim3(8, 64, 3), 256, 0, stream>>>(K8, u, rc0);   // raw K^T 1
        sk_v<<<dim3(32, 1, 3), 256, 0, stream>>>(rc0, vb);           // v_1
        for (int t = 1; t <= 100; t++) {
            sk_iter<<<dim3(256, 1, 3), 512, 0, stream>>>(K8, vb, rcp, u, t == 100 ? 1 : 0);
            if (t < 100)
                sk_reduce<<<dim3(128, 1, 3), 256, 0, stream>>>(rcp, vb);
        }
        // after t=100: u = u_100, vb = v_100
        sk_wsum<<<dim3(256, 1, 3), 256, 0, stream>>>(K8, vb, u, wacc);
    } else {
        for (int tf = 0; tf < 3; tf++) {
            hipMemsetAsync(rc0, 0, 1ull * NN * sizeof(float), stream);
            sk_init_u<<<NN / 256, 256, 0, stream>>>(u);
            sk_build_k<<<dim3(128, 128, 1), 256, 0, stream>>>(pts[tf][0], pts[tf][1], K8);
            sk_colsum<<<dim3(8, 64, 1), 256, 0, stream>>>(K8, u, rc0);
            sk_v<<<dim3(32, 1, 1), 256, 0, stream>>>(rc0, vb);
            for (int t = 1; t <= 100; t++) {
                sk_iter<<<dim3(256, 1, 1), 512, 0, stream>>>(K8, vb, rcp, u, t == 100 ? 1 : 0);
                if (t < 100)
                    sk_reduce<<<dim3(128, 1, 1), 256, 0, stream>>>(rcp, vb);
            }
            sk_wsum<<<dim3(256, 1, 1), 256, 0, stream>>>(K8, vb, u, &wacc[tf]);
        }
    }
    sk_combine<<<1, 64, 0, stream>>>(wacc, out);
}

// Round 5
// 6094.584 us; speedup vs baseline: 7.7426x; 6.6732x over previous
//
#include <hip/hip_runtime.h>

#define NN 8192
#define DD 32
// stagger-padded LDS index: +4 floats of pad per 16 (keeps 16B alignment)
#define SIDX(c) ((c) + 4 * ((c) >> 4))

constexpr float kEps   = 0.1f;
constexpr float kStab  = 1e-8f;
constexpr float kMass  = 1.0f / 8192.0f;     // mu = nu = 1/n
constexpr float kInvSc = 1.0f / 256.0f;      // K stored as fp8 of 256*K
constexpr float kLnSc  = 5.545177444479562f; // ln(256)

typedef float v2f __attribute__((ext_vector_type(2)));

__device__ inline void cvt8x4(unsigned int w, float* out) {
    v2f lo = __builtin_amdgcn_cvt_pk_f32_fp8(w, false);
    v2f hi = __builtin_amdgcn_cvt_pk_f32_fp8(w, true);
    out[0] = lo.x; out[1] = lo.y; out[2] = hi.x; out[3] = hi.y;
}
__device__ inline void cvt16(uint4 kk, float* f) {
    cvt8x4(kk.x, f); cvt8x4(kk.y, f + 4); cvt8x4(kk.z, f + 8); cvt8x4(kk.w, f + 12);
}
__device__ inline unsigned int pack8x4(float a, float b, float c, float d) {
    int v = 0;
    v = __builtin_amdgcn_cvt_pk_fp8_f32(a, b, v, false);
    v = __builtin_amdgcn_cvt_pk_fp8_f32(c, d, v, true);
    return (unsigned int)v;
}
// dot of 16 fp8 values against v (by-value float4s -> SROA-friendly)
__device__ inline float dot16v(uint4 kk, float4 a, float4 b, float4 c, float4 d) {
    float f[16];
    cvt16(kk, f);
    float s = 0.f;
    s = fmaf(f[0],  a.x, s); s = fmaf(f[1],  a.y, s);
    s = fmaf(f[2],  a.z, s); s = fmaf(f[3],  a.w, s);
    s = fmaf(f[4],  b.x, s); s = fmaf(f[5],  b.y, s);
    s = fmaf(f[6],  b.z, s); s = fmaf(f[7],  b.w, s);
    s = fmaf(f[8],  c.x, s); s = fmaf(f[9],  c.y, s);
    s = fmaf(f[10], c.z, s); s = fmaf(f[11], c.w, s);
    s = fmaf(f[12], d.x, s); s = fmaf(f[13], d.y, s);
    s = fmaf(f[14], d.z, s); s = fmaf(f[15], d.w, s);
    return s;
}
// col-acc += f8 * ur, accumulators as float4 refs (SROA-friendly)
__device__ inline void axpy16v(uint4 kk, float ur,
                               float4& c0, float4& c1, float4& c2, float4& c3) {
    float f[16];
    cvt16(kk, f);
    c0.x = fmaf(f[0],  ur, c0.x); c0.y = fmaf(f[1],  ur, c0.y);
    c0.z = fmaf(f[2],  ur, c0.z); c0.w = fmaf(f[3],  ur, c0.w);
    c1.x = fmaf(f[4],  ur, c1.x); c1.y = fmaf(f[5],  ur, c1.y);
    c1.z = fmaf(f[6],  ur, c1.z); c1.w = fmaf(f[7],  ur, c1.w);
    c2.x = fmaf(f[8],  ur, c2.x); c2.y = fmaf(f[9],  ur, c2.y);
    c2.z = fmaf(f[10], ur, c2.z); c2.w = fmaf(f[11], ur, c2.w);
    c3.x = fmaf(f[12], ur, c3.x); c3.y = fmaf(f[13], ur, c3.y);
    c3.z = fmaf(f[14], ur, c3.z); c3.w = fmaf(f[15], ur, c3.w);
}

// ---------------------------------------------------------------- init u = 1
__global__ void sk_init_u(float* __restrict__ u) {
    u[blockIdx.x * 256 + threadIdx.x] = 1.0f;
}

// -------------------------------- build K8 = fp8(256*exp(-cost/eps)) for one pair
__global__ __launch_bounds__(256) void sk_build_k(const float* __restrict__ X,
                                                  const float* __restrict__ Y,
                                                  unsigned char* __restrict__ K) {
    __shared__ float xs[DD * 64];
    __shared__ float ys[DD * 64];
    __shared__ float sx[64], sy[64];
    const int t  = threadIdx.x;
    const int r0 = blockIdx.y * 64, c0 = blockIdx.x * 64;

    for (int idx = t; idx < DD * 64; idx += 256) {
        int d = idx >> 6, row = idx & 63;
        xs[idx] = X[(size_t)(r0 + row) * DD + d];
        ys[idx] = Y[(size_t)(c0 + row) * DD + d];
    }
    __syncthreads();
    if (t < 64) {
        float s = 0.f;
        for (int d = 0; d < DD; d++) { float v = xs[d * 64 + t]; s = fmaf(v, v, s); }
        sx[t] = s;
    } else if (t < 128) {
        int q = t - 64; float s = 0.f;
        for (int d = 0; d < DD; d++) { float v = ys[d * 64 + q]; s = fmaf(v, v, s); }
        sy[q] = s;
    }
    __syncthreads();

    const int tr = t >> 4, tc = t & 15;
    float acc[4][4] = {};
    for (int d = 0; d < DD; d++) {
        const float4 xa = *reinterpret_cast<const float4*>(&xs[d * 64 + 4 * tr]);
        const float4 yb = *reinterpret_cast<const float4*>(&ys[d * 64 + 4 * tc]);
        const float xav[4] = {xa.x, xa.y, xa.z, xa.w};
        const float ybv[4] = {yb.x, yb.y, yb.z, yb.w};
#pragma unroll
        for (int a = 0; a < 4; a++)
#pragma unroll
            for (int b = 0; b < 4; b++) acc[a][b] = fmaf(xav[a], ybv[b], acc[a][b]);
    }
#pragma unroll
    for (int a = 0; a < 4; a++) {
        const int r = r0 + 4 * tr + a;
        const float sxa = sx[4 * tr + a];
        float e[4];
#pragma unroll
        for (int b = 0; b < 4; b++) {
            float cost = sxa + sy[4 * tc + b] - 2.0f * acc[a][b];
            cost = fmaxf(cost, 0.0f);
            e[b] = expf(fmaf(-10.0f, cost, kLnSc));   // 256 * exp(-cost/eps)
        }
        *reinterpret_cast<unsigned int*>(&K[(size_t)r * NN + c0 + 4 * tc]) =
            pack8x4(e[0], e[1], e[2], e[3]);
    }
}

// -------------------------------- initial column sums: rc[z] += K[z]^T u[z] (u = 1)
// one-shot, 64 contenders/address — benign atomic regime (round-0 evidence).
__global__ __launch_bounds__(256) void sk_colsum(const unsigned char* __restrict__ K8,
                                                 const float* __restrict__ u,
                                                 float* __restrict__ rc_out) {
    __shared__ float us[128];
    __shared__ float red[4 * 1280];   // 4 waves x staggered 1024
    const int t = threadIdx.x, lane = t & 63, w = t >> 6;
    const int z = blockIdx.z;
    const int c0 = blockIdx.x * 1024, r0 = blockIdx.y * 128;
    const unsigned char* K = K8 + (size_t)z * NN * NN;
    if (t < 128) us[t] = u[z * NN + r0 + t];
    __syncthreads();

    float acc[16] = {};
    const unsigned char* p = K + (size_t)(r0 + 32 * w) * NN + c0 + 16 * lane;
    for (int i = 0; i < 32; i += 4) {
        uint4 k0 = *reinterpret_cast<const uint4*>(p);
        uint4 k1 = *reinterpret_cast<const uint4*>(p + (size_t)NN);
        uint4 k2 = *reinterpret_cast<const uint4*>(p + (size_t)2 * NN);
        uint4 k3 = *reinterpret_cast<const uint4*>(p + (size_t)3 * NN);
        p += (size_t)4 * NN;
        const float u0 = us[32 * w + i + 0], u1 = us[32 * w + i + 1];
        const float u2 = us[32 * w + i + 2], u3 = us[32 * w + i + 3];
        float f[16];
        cvt16(k0, f);
#pragma unroll
        for (int j = 0; j < 16; j++) acc[j] = fmaf(f[j], u0, acc[j]);
        cvt16(k1, f);
#pragma unroll
        for (int j = 0; j < 16; j++) acc[j] = fmaf(f[j], u1, acc[j]);
        cvt16(k2, f);
#pragma unroll
        for (int j = 0; j < 16; j++) acc[j] = fmaf(f[j], u2, acc[j]);
        cvt16(k3, f);
#pragma unroll
        for (int j = 0; j < 16; j++) acc[j] = fmaf(f[j], u3, acc[j]);
    }
    float* rw = &red[w * 1280 + 20 * lane];   // SIDX(16*lane) = 20*lane
#pragma unroll
    for (int g = 0; g < 4; g++) {
        float4 v = {acc[4 * g + 0], acc[4 * g + 1], acc[4 * g + 2], acc[4 * g + 3]};
        *reinterpret_cast<float4*>(rw + 4 * g) = v;
    }
    __syncthreads();
    for (int c = t; c < 1024; c += 256) {
        const int sc = SIDX(c);
        const float s = red[sc] + red[1280 + sc] + red[2560 + sc] + red[3840 + sc];
        atomicAdd(&rc_out[z * NN + c0 + c], s);
    }
}

// -------------------------------- v[c] = m / (raw[c]/256 + stab)  (once, after colsum)
__global__ void sk_v(const float* __restrict__ rc, float* __restrict__ v) {
    const int i = (blockIdx.z * gridDim.x + blockIdx.x) * 256 + threadIdx.x;
    v[i] = kMass * __builtin_amdgcn_rcpf(fmaf(rc[i], kInvSc, kStab));
}

// -------------------------------- fused iteration, register-resident K, bounded pressure:
// 512 threads = 8 waves. Block owns 32 rows x 8192 cols. Wave w owns col strip
// [1024w, 1024w+1024); lane owns 16 fixed cols (one uint4/row) for ALL rows.
// Group loop is NOT unrolled (pragma unroll 1) with an explicit 1-deep prefetch
// double-buffer, so at most 2 K-groups (32 VGPR) are in flight -- total live
// ~96 VGPR, no scratch spill (round-4 lesson: full unroll hoisted 8 groups of
// loads -> 128-reg cap blown -> 550 MB/dispatch scratch traffic).
// K is read from HBM exactly once; col partials stored non-atomically to
// rcp[z][bid][8192]; row sums cross-wave reduced via LDS, u written by wave 0.
__global__ __launch_bounds__(512, 2) void sk_iter(const unsigned char* __restrict__ K8,
                                                  const float* __restrict__ v_in,
                                                  float* __restrict__ rcp,
                                                  float* __restrict__ u_out,
                                                  int last) {
    __shared__ float cs[10240];        // staggered 8192: colsum drain buffer
    __shared__ float red[8][8][4];     // group x wave x row partial rowsums
    const int t = threadIdx.x, lane = t & 63, w = t >> 6;
    const int z = blockIdx.z;
    const unsigned char* K = K8 + (size_t)z * NN * NN;
    const int rowbase = blockIdx.x * 32;
    const int c0 = 1024 * w;

    // ---- v for this lane's 16 columns, in registers
    float4 va, vb, vc, vd;
    {
        const float* vz = v_in + (size_t)z * NN + c0 + 16 * lane;
        va = reinterpret_cast<const float4*>(vz)[0];
        vb = reinterpret_cast<const float4*>(vz)[1];
        vc = reinterpret_cast<const float4*>(vz)[2];
        vd = reinterpret_cast<const float4*>(vz)[3];
    }

    const unsigned char* kp = K + (size_t)rowbase * NN + c0 + 16 * lane;
    // prefetch group 0 (4 rows x 16 cols of packed fp8)
    uint4 n0 = *reinterpret_cast<const uint4*>(kp);
    uint4 n1 = *reinterpret_cast<const uint4*>(kp + (size_t)NN);
    uint4 n2 = *reinterpret_cast<const uint4*>(kp + (size_t)2 * NN);
    uint4 n3 = *reinterpret_cast<const uint4*>(kp + (size_t)3 * NN);

    float4 ca0 = {0,0,0,0}, ca1 = {0,0,0,0}, ca2 = {0,0,0,0}, ca3 = {0,0,0,0};
#pragma unroll 1
    for (int g = 0; g < 8; g++) {
        const uint4 k0 = n0, k1 = n1, k2 = n2, k3 = n3;
        if (g < 7) {   // issue next group's loads before computing on current
            const unsigned char* np = kp + (size_t)(4 * (g + 1)) * NN;
            n0 = *reinterpret_cast<const uint4*>(np);
            n1 = *reinterpret_cast<const uint4*>(np + (size_t)NN);
            n2 = *reinterpret_cast<const uint4*>(np + (size_t)2 * NN);
            n3 = *reinterpret_cast<const uint4*>(np + (size_t)3 * NN);
        }
        // phase 1: per-lane partial row sums -> wave reduce -> LDS
        float p0 = dot16v(k0, va, vb, vc, vd);
        float p1 = dot16v(k1, va, vb, vc, vd);
        float p2 = dot16v(k2, va, vb, vc, vd);
        float p3 = dot16v(k3, va, vb, vc, vd);
#pragma unroll
        for (int off = 32; off > 0; off >>= 1) {
            p0 += __shfl_down(p0, off);
            p1 += __shfl_down(p1, off);
            p2 += __shfl_down(p2, off);
            p3 += __shfl_down(p3, off);
        }
        if (lane == 0) {
            red[g][w][0] = p0; red[g][w][1] = p1;
            red[g][w][2] = p2; red[g][w][3] = p3;
        }
        __syncthreads();
        // every wave computes u for the 4 rows (identical fp math, no 2nd sync)
        float ug[4];
#pragma unroll
        for (int r = 0; r < 4; r++) {
            float s = 0.f;
#pragma unroll
            for (int ww = 0; ww < 8; ww++) s += red[g][ww][r];
            ug[r] = kMass / (s * kInvSc + kStab);
            if (w == 0 && lane == r) u_out[(size_t)z * NN + rowbase + 4 * g + r] = ug[r];
        }
        // phase 2: re-convert the SAME registers, accumulate column partials
        axpy16v(k0, ug[0], ca0, ca1, ca2, ca3);
        axpy16v(k1, ug[1], ca0, ca1, ca2, ca3);
        axpy16v(k2, ug[2], ca0, ca1, ca2, ca3);
        axpy16v(k3, ug[3], ca0, ca1, ca2, ca3);
    }
    if (last) return;   // uniform: final iteration needs no next colsum

    // ---- drain: stage strip partials in LDS, then plain coalesced stores
    {
        float* b0 = &cs[SIDX(c0 + 16 * lane)];   // base%16==0 -> SIDX(base+j)=SIDX(base)+j
        *reinterpret_cast<float4*>(b0 + 0)  = ca0;
        *reinterpret_cast<float4*>(b0 + 4)  = ca1;
        *reinterpret_cast<float4*>(b0 + 8)  = ca2;
        *reinterpret_cast<float4*>(b0 + 12) = ca3;
    }
    __syncthreads();
    float* rp = rcp + ((size_t)z * 256 + blockIdx.x) * NN;
    for (int i = 4 * t; i < NN; i += 2048) {             // 4 x float4 per thread
        float4 v4 = *reinterpret_cast<const float4*>(&cs[SIDX(i)]);
        *reinterpret_cast<float4*>(&rp[i]) = v4;
    }
}

// -------------------------------- fold 256 block partials -> v (next iteration)
// grid (128, 1, nb), 256 threads: block owns 64 cols; thread quarter-sums 64 rows.
__global__ __launch_bounds__(256) void sk_reduce(const float* __restrict__ rcp,
                                                 float* __restrict__ v_out) {
    __shared__ float sred[4][64];
    const int t = threadIdx.x, tc = t & 63, tq = t >> 6;
    const int z = blockIdx.z;
    const int c = blockIdx.x * 64 + tc;
    const float* base = rcp + (size_t)z * 256 * NN + c;
    float acc = 0.f;
#pragma unroll 8
    for (int r = tq * 64; r < tq * 64 + 64; r++) acc += base[(size_t)r * NN];
    sred[tq][tc] = acc;
    __syncthreads();
    if (t < 64) {
        const float s = sred[0][t] + sred[1][t] + sred[2][t] + sred[3][t];
        v_out[(size_t)z * NN + blockIdx.x * 64 + t] =
            kMass * __builtin_amdgcn_rcpf(fmaf(s, kInvSc, kStab));
    }
}

// -------------------------------- w[z] = sum u_i K_ij v_j cost_ij, cost = -eps*ln(K)
__global__ __launch_bounds__(256) void sk_wsum(const unsigned char* __restrict__ K8,
                                               const float* __restrict__ v_in,
                                               const float* __restrict__ u,
                                               double* __restrict__ acc_out) {
    __shared__ float vs[10240];
    __shared__ double wred[4];
    const int t = threadIdx.x;
    const int z = blockIdx.z;
    const unsigned char* K = K8 + (size_t)z * NN * NN;
    const float* v = v_in + (size_t)z * NN;
#pragma unroll
    for (int q = 0; q < 8; q++) {
        const int j = 4 * t + 1024 * q;
        *reinterpret_cast<float4*>(&vs[SIDX(j)]) = *reinterpret_cast<const float4*>(v + j);
    }
    __syncthreads();

    const int lane = t & 63, w = t >> 6;
    const int rbase = blockIdx.x * 32 + 8 * w;
    float pr[8] = {};
    const unsigned char* rp = K + (size_t)rbase * NN + 16 * lane;
    for (int s = 0; s < 8; s++) {
        const float* vp = &vs[20 * lane + 1280 * s];
        float vv[16];
#pragma unroll
        for (int g = 0; g < 4; g++) {
            float4 v4 = *reinterpret_cast<const float4*>(vp + 4 * g);
            vv[4 * g] = v4.x; vv[4 * g + 1] = v4.y; vv[4 * g + 2] = v4.z; vv[4 * g + 3] = v4.w;
        }
        const unsigned char* ps = rp + 1024 * s;
#pragma unroll
        for (int r = 0; r < 8; r++) {
            uint4 kk = *reinterpret_cast<const uint4*>(ps + (size_t)r * NN);
            float f[16];
            cvt16(kk, f);
            float a = pr[r];
#pragma unroll
            for (int j = 0; j < 16; j++) {
                // term k*v*ln(k): zero when f==0 since f*v==0
                a = fmaf(f[j] * vv[j], __logf(fmaxf(f[j], 1e-30f) * kInvSc), a);
            }
            pr[r] = a;
        }
    }
    double lacc = 0.0;
#pragma unroll
    for (int r = 0; r < 8; r++)
        lacc += (double)(u[(size_t)z * NN + rbase + r] * pr[r]);
    lacc *= (double)kInvSc;
    for (int off = 32; off > 0; off >>= 1) lacc += __shfl_down(lacc, off);
    if (lane == 0) wred[w] = lacc;
    __syncthreads();
    if (t == 0) {
        double total = -(double)kEps * (wred[0] + wred[1] + wred[2] + wred[3]);
        atomicAdd(&acc_out[z], total);
    }
}

// ------------------------------------------------- combine
__global__ void sk_combine(const double* __restrict__ acc, float* __restrict__ out) {
    if (threadIdx.x == 0)
        out[0] = (float)((acc[0] - 0.5 * acc[1] - 0.5 * acc[2]) / 8192.0);
}

extern "C" void kernel_launch(void* const* d_in, const int* in_sizes, int n_in,
                              void* d_out, int out_size, void* d_ws, size_t ws_size,
                              hipStream_t stream) {
    const float* src = (const float*)d_in[0];
    const float* tgt = (const float*)d_in[1];
    float* out = (float*)d_out;
    char* ws = (char*)d_ws;

    // batched needs: 3 K matrices + 3x256x8192 partials + vectors
    const size_t need3 = 3ull * NN * NN + 3ull * 256 * NN * 4 + 16ull * NN * 4 + 1024;
    const bool batched = ws_size >= need3;
    const int B = batched ? 3 : 1;

    unsigned char* K8 = (unsigned char*)ws;
    float*  rcp  = (float*)(ws + (size_t)B * NN * NN);
    float*  vb   = rcp + (size_t)B * 256 * NN;
    float*  u    = vb + (size_t)B * NN;
    float*  rc0  = u + (size_t)B * NN;
    double* wacc = (double*)(rc0 + (size_t)B * NN);

    hipMemsetAsync(wacc, 0, 3 * sizeof(double), stream);
    const float* pts[3][2] = {{src, tgt}, {src, src}, {tgt, tgt}};

    if (batched) {
        hipMemsetAsync(rc0, 0, 3ull * NN * sizeof(float), stream);
        sk_init_u<<<3 * NN / 256, 256, 0, stream>>>(u);
        for (int i = 0; i < 3; i++)
            sk_build_k<<<dim3(128, 128, 1), 256, 0, stream>>>(pts[i][0], pts[i][1],
                                                              K8 + (size_t)i * NN * NN);
        sk_colsum<<<dim3(8, 64, 3), 256, 0, stream>>>(K8, u, rc0);   // raw K^T 1
        sk_v<<<dim3(32, 1, 3), 256, 0, stream>>>(rc0, vb);           // v_1
        for (int t = 1; t <= 100; t++) {
            sk_iter<<<dim3(256, 1, 3), 512, 0, stream>>>(K8, vb, rcp, u, t == 100 ? 1 : 0);
            if (t < 100)
                sk_reduce<<<dim3(128, 1, 3), 256, 0, stream>>>(rcp, vb);
        }
        // after t=100: u = u_100, vb = v_100
        sk_wsum<<<dim3(256, 1, 3), 256, 0, stream>>>(K8, vb, u, wacc);
    } else {
        for (int tf = 0; tf < 3; tf++) {
            hipMemsetAsync(rc0, 0, 1ull * NN * sizeof(float), stream);
            sk_init_u<<<NN / 256, 256, 0, stream>>>(u);
            sk_build_k<<<dim3(128, 128, 1), 256, 0, stream>>>(pts[tf][0], pts[tf][1], K8);
            sk_colsum<<<dim3(8, 64, 1), 256, 0, stream>>>(K8, u, rc0);
            sk_v<<<dim3(32, 1, 1), 256, 0, stream>>>(rc0, vb);
            for (int t = 1; t <= 100; t++) {
                sk_iter<<<dim3(256, 1, 1), 512, 0, stream>>>(K8, vb, rcp, u, t == 100 ? 1 : 0);
                if (t < 100)
                    sk_reduce<<<dim3(128, 1, 1), 256, 0, stream>>>(rcp, vb);
            }
            sk_wsum<<<dim3(256, 1, 1), 256, 0, stream>>>(K8, vb, u, &wacc[tf]);
        }
    }
    sk_combine<<<1, 64, 0, stream>>>(wacc, out);
}

// Round 6
// 5921.476 us; speedup vs baseline: 7.9689x; 1.0292x over previous
//
#include <hip/hip_runtime.h>

#define NN 8192
#define DD 32
// stagger-padded LDS index: +4 floats of pad per 16 (keeps 16B alignment)
#define SIDX(c) ((c) + 4 * ((c) >> 4))

constexpr float kEps   = 0.1f;
constexpr float kStab  = 1e-8f;
constexpr float kMass  = 1.0f / 8192.0f;     // mu = nu = 1/n
constexpr float kInvSc = 1.0f / 256.0f;      // K stored as fp8 of 256*K
constexpr float kLnSc  = 5.545177444479562f; // ln(256)

typedef float v2f __attribute__((ext_vector_type(2)));

__device__ inline void cvt8x4(unsigned int w, float* out) {
    v2f lo = __builtin_amdgcn_cvt_pk_f32_fp8(w, false);
    v2f hi = __builtin_amdgcn_cvt_pk_f32_fp8(w, true);
    out[0] = lo.x; out[1] = lo.y; out[2] = hi.x; out[3] = hi.y;
}
__device__ inline void cvt16(uint4 kk, float* f) {
    cvt8x4(kk.x, f); cvt8x4(kk.y, f + 4); cvt8x4(kk.z, f + 8); cvt8x4(kk.w, f + 12);
}
__device__ inline unsigned int pack8x4(float a, float b, float c, float d) {
    int v = 0;
    v = __builtin_amdgcn_cvt_pk_fp8_f32(a, b, v, false);
    v = __builtin_amdgcn_cvt_pk_fp8_f32(c, d, v, true);
    return (unsigned int)v;
}
// dot of 16 fp8 values against v (by-value float4s -> SROA-friendly)
__device__ inline float dot16v(uint4 kk, float4 a, float4 b, float4 c, float4 d) {
    float f[16];
    cvt16(kk, f);
    float s = 0.f;
    s = fmaf(f[0],  a.x, s); s = fmaf(f[1],  a.y, s);
    s = fmaf(f[2],  a.z, s); s = fmaf(f[3],  a.w, s);
    s = fmaf(f[4],  b.x, s); s = fmaf(f[5],  b.y, s);
    s = fmaf(f[6],  b.z, s); s = fmaf(f[7],  b.w, s);
    s = fmaf(f[8],  c.x, s); s = fmaf(f[9],  c.y, s);
    s = fmaf(f[10], c.z, s); s = fmaf(f[11], c.w, s);
    s = fmaf(f[12], d.x, s); s = fmaf(f[13], d.y, s);
    s = fmaf(f[14], d.z, s); s = fmaf(f[15], d.w, s);
    return s;
}
// col-acc += f8 * ur, accumulators as float4 refs (SROA-friendly)
__device__ inline void axpy16v(uint4 kk, float ur,
                               float4& c0, float4& c1, float4& c2, float4& c3) {
    float f[16];
    cvt16(kk, f);
    c0.x = fmaf(f[0],  ur, c0.x); c0.y = fmaf(f[1],  ur, c0.y);
    c0.z = fmaf(f[2],  ur, c0.z); c0.w = fmaf(f[3],  ur, c0.w);
    c1.x = fmaf(f[4],  ur, c1.x); c1.y = fmaf(f[5],  ur, c1.y);
    c1.z = fmaf(f[6],  ur, c1.z); c1.w = fmaf(f[7],  ur, c1.w);
    c2.x = fmaf(f[8],  ur, c2.x); c2.y = fmaf(f[9],  ur, c2.y);
    c2.z = fmaf(f[10], ur, c2.z); c2.w = fmaf(f[11], ur, c2.w);
    c3.x = fmaf(f[12], ur, c3.x); c3.y = fmaf(f[13], ur, c3.y);
    c3.z = fmaf(f[14], ur, c3.z); c3.w = fmaf(f[15], ur, c3.w);
}

// ---------------------------------------------------------------- init u = 1
__global__ void sk_init_u(float* __restrict__ u) {
    u[blockIdx.x * 256 + threadIdx.x] = 1.0f;
}

// -------------------------------- build K8 = fp8(256*exp(-cost/eps)) for one pair
// __expf (v_exp_f32) instead of libm expf: round-5 PMC showed 73% VALUBusy at 6%
// HBM -- transcendental-bound. fp8 quantization (~6% rel) dwarfs __expf's ~1e-5.
__global__ __launch_bounds__(256) void sk_build_k(const float* __restrict__ X,
                                                  const float* __restrict__ Y,
                                                  unsigned char* __restrict__ K) {
    __shared__ float xs[DD * 64];
    __shared__ float ys[DD * 64];
    __shared__ float sx[64], sy[64];
    const int t  = threadIdx.x;
    const int r0 = blockIdx.y * 64, c0 = blockIdx.x * 64;

    for (int idx = t; idx < DD * 64; idx += 256) {
        int d = idx >> 6, row = idx & 63;
        xs[idx] = X[(size_t)(r0 + row) * DD + d];
        ys[idx] = Y[(size_t)(c0 + row) * DD + d];
    }
    __syncthreads();
    if (t < 64) {
        float s = 0.f;
        for (int d = 0; d < DD; d++) { float v = xs[d * 64 + t]; s = fmaf(v, v, s); }
        sx[t] = s;
    } else if (t < 128) {
        int q = t - 64; float s = 0.f;
        for (int d = 0; d < DD; d++) { float v = ys[d * 64 + q]; s = fmaf(v, v, s); }
        sy[q] = s;
    }
    __syncthreads();

    const int tr = t >> 4, tc = t & 15;
    float acc[4][4] = {};
    for (int d = 0; d < DD; d++) {
        const float4 xa = *reinterpret_cast<const float4*>(&xs[d * 64 + 4 * tr]);
        const float4 yb = *reinterpret_cast<const float4*>(&ys[d * 64 + 4 * tc]);
        const float xav[4] = {xa.x, xa.y, xa.z, xa.w};
        const float ybv[4] = {yb.x, yb.y, yb.z, yb.w};
#pragma unroll
        for (int a = 0; a < 4; a++)
#pragma unroll
            for (int b = 0; b < 4; b++) acc[a][b] = fmaf(xav[a], ybv[b], acc[a][b]);
    }
#pragma unroll
    for (int a = 0; a < 4; a++) {
        const int r = r0 + 4 * tr + a;
        const float sxa = sx[4 * tr + a];
        float e[4];
#pragma unroll
        for (int b = 0; b < 4; b++) {
            float cost = sxa + sy[4 * tc + b] - 2.0f * acc[a][b];
            cost = fmaxf(cost, 0.0f);
            e[b] = __expf(fmaf(-10.0f, cost, kLnSc));   // 256 * exp(-cost/eps)
        }
        *reinterpret_cast<unsigned int*>(&K[(size_t)r * NN + c0 + 4 * tc]) =
            pack8x4(e[0], e[1], e[2], e[3]);
    }
}

// -------------------------------- initial column sums: rc[z] += K[z]^T u[z] (u = 1)
// one-shot, 64 contenders/address — benign atomic regime (round-0 evidence).
__global__ __launch_bounds__(256) void sk_colsum(const unsigned char* __restrict__ K8,
                                                 const float* __restrict__ u,
                                                 float* __restrict__ rc_out) {
    __shared__ float us[128];
    __shared__ float red[4 * 1280];   // 4 waves x staggered 1024
    const int t = threadIdx.x, lane = t & 63, w = t >> 6;
    const int z = blockIdx.z;
    const int c0 = blockIdx.x * 1024, r0 = blockIdx.y * 128;
    const unsigned char* K = K8 + (size_t)z * NN * NN;
    if (t < 128) us[t] = u[z * NN + r0 + t];
    __syncthreads();

    float acc[16] = {};
    const unsigned char* p = K + (size_t)(r0 + 32 * w) * NN + c0 + 16 * lane;
    for (int i = 0; i < 32; i += 4) {
        uint4 k0 = *reinterpret_cast<const uint4*>(p);
        uint4 k1 = *reinterpret_cast<const uint4*>(p + (size_t)NN);
        uint4 k2 = *reinterpret_cast<const uint4*>(p + (size_t)2 * NN);
        uint4 k3 = *reinterpret_cast<const uint4*>(p + (size_t)3 * NN);
        p += (size_t)4 * NN;
        const float u0 = us[32 * w + i + 0], u1 = us[32 * w + i + 1];
        const float u2 = us[32 * w + i + 2], u3 = us[32 * w + i + 3];
        float f[16];
        cvt16(k0, f);
#pragma unroll
        for (int j = 0; j < 16; j++) acc[j] = fmaf(f[j], u0, acc[j]);
        cvt16(k1, f);
#pragma unroll
        for (int j = 0; j < 16; j++) acc[j] = fmaf(f[j], u1, acc[j]);
        cvt16(k2, f);
#pragma unroll
        for (int j = 0; j < 16; j++) acc[j] = fmaf(f[j], u2, acc[j]);
        cvt16(k3, f);
#pragma unroll
        for (int j = 0; j < 16; j++) acc[j] = fmaf(f[j], u3, acc[j]);
    }
    float* rw = &red[w * 1280 + 20 * lane];   // SIDX(16*lane) = 20*lane
#pragma unroll
    for (int g = 0; g < 4; g++) {
        float4 v = {acc[4 * g + 0], acc[4 * g + 1], acc[4 * g + 2], acc[4 * g + 3]};
        *reinterpret_cast<float4*>(rw + 4 * g) = v;
    }
    __syncthreads();
    for (int c = t; c < 1024; c += 256) {
        const int sc = SIDX(c);
        const float s = red[sc] + red[1280 + sc] + red[2560 + sc] + red[3840 + sc];
        atomicAdd(&rc_out[z * NN + c0 + c], s);
    }
}

// -------------------------------- v[c] = m / (raw[c]/256 + stab)  (once, after colsum)
__global__ void sk_v(const float* __restrict__ rc, float* __restrict__ v) {
    const int i = (blockIdx.z * gridDim.x + blockIdx.x) * 256 + threadIdx.x;
    v[i] = kMass * __builtin_amdgcn_rcpf(fmaf(rc[i], kInvSc, kStab));
}

// -------------------------------- fused iteration, register-resident K, bounded pressure:
// 512 threads = 8 waves. Block owns 32 rows x 8192 cols. Wave w owns col strip
// [1024w, 1024w+1024); lane owns 16 fixed cols (one uint4/row) for ALL rows.
// Group loop is NOT unrolled (pragma unroll 1) with an explicit 1-deep prefetch
// double-buffer, so at most 2 K-groups (32 VGPR) are in flight -- total live
// ~96 VGPR, no scratch spill (round-4 lesson: full unroll hoisted 8 groups of
// loads -> 128-reg cap blown -> 550 MB/dispatch scratch traffic).
// NOTE: deeper prefetch is pointless here -- each group's __syncthreads drains
// vmcnt(0), so per-wave MLP is structurally capped at one group of loads.
// K is read from HBM exactly once; col partials stored non-atomically to
// rcp[z][bid][8192]; row sums cross-wave reduced via LDS, u written by wave 0.
__global__ __launch_bounds__(512, 2) void sk_iter(const unsigned char* __restrict__ K8,
                                                  const float* __restrict__ v_in,
                                                  float* __restrict__ rcp,
                                                  float* __restrict__ u_out,
                                                  int last) {
    __shared__ float cs[10240];        // staggered 8192: colsum drain buffer
    __shared__ float red[8][8][4];     // group x wave x row partial rowsums
    const int t = threadIdx.x, lane = t & 63, w = t >> 6;
    const int z = blockIdx.z;
    const unsigned char* K = K8 + (size_t)z * NN * NN;
    const int rowbase = blockIdx.x * 32;
    const int c0 = 1024 * w;

    // ---- v for this lane's 16 columns, in registers
    float4 va, vb, vc, vd;
    {
        const float* vz = v_in + (size_t)z * NN + c0 + 16 * lane;
        va = reinterpret_cast<const float4*>(vz)[0];
        vb = reinterpret_cast<const float4*>(vz)[1];
        vc = reinterpret_cast<const float4*>(vz)[2];
        vd = reinterpret_cast<const float4*>(vz)[3];
    }

    const unsigned char* kp = K + (size_t)rowbase * NN + c0 + 16 * lane;
    // prefetch group 0 (4 rows x 16 cols of packed fp8)
    uint4 n0 = *reinterpret_cast<const uint4*>(kp);
    uint4 n1 = *reinterpret_cast<const uint4*>(kp + (size_t)NN);
    uint4 n2 = *reinterpret_cast<const uint4*>(kp + (size_t)2 * NN);
    uint4 n3 = *reinterpret_cast<const uint4*>(kp + (size_t)3 * NN);

    float4 ca0 = {0,0,0,0}, ca1 = {0,0,0,0}, ca2 = {0,0,0,0}, ca3 = {0,0,0,0};
#pragma unroll 1
    for (int g = 0; g < 8; g++) {
        const uint4 k0 = n0, k1 = n1, k2 = n2, k3 = n3;
        if (g < 7) {   // issue next group's loads before computing on current
            const unsigned char* np = kp + (size_t)(4 * (g + 1)) * NN;
            n0 = *reinterpret_cast<const uint4*>(np);
            n1 = *reinterpret_cast<const uint4*>(np + (size_t)NN);
            n2 = *reinterpret_cast<const uint4*>(np + (size_t)2 * NN);
            n3 = *reinterpret_cast<const uint4*>(np + (size_t)3 * NN);
        }
        // phase 1: per-lane partial row sums -> wave reduce -> LDS
        float p0 = dot16v(k0, va, vb, vc, vd);
        float p1 = dot16v(k1, va, vb, vc, vd);
        float p2 = dot16v(k2, va, vb, vc, vd);
        float p3 = dot16v(k3, va, vb, vc, vd);
#pragma unroll
        for (int off = 32; off > 0; off >>= 1) {
            p0 += __shfl_down(p0, off);
            p1 += __shfl_down(p1, off);
            p2 += __shfl_down(p2, off);
            p3 += __shfl_down(p3, off);
        }
        if (lane == 0) {
            red[g][w][0] = p0; red[g][w][1] = p1;
            red[g][w][2] = p2; red[g][w][3] = p3;
        }
        __syncthreads();
        // every wave computes u for the 4 rows (identical fp math, no 2nd sync)
        float ug[4];
#pragma unroll
        for (int r = 0; r < 4; r++) {
            float s = 0.f;
#pragma unroll
            for (int ww = 0; ww < 8; ww++) s += red[g][ww][r];
            ug[r] = kMass / (s * kInvSc + kStab);
            if (w == 0 && lane == r) u_out[(size_t)z * NN + rowbase + 4 * g + r] = ug[r];
        }
        // phase 2: re-convert the SAME registers, accumulate column partials
        axpy16v(k0, ug[0], ca0, ca1, ca2, ca3);
        axpy16v(k1, ug[1], ca0, ca1, ca2, ca3);
        axpy16v(k2, ug[2], ca0, ca1, ca2, ca3);
        axpy16v(k3, ug[3], ca0, ca1, ca2, ca3);
    }
    if (last) return;   // uniform: final iteration needs no next colsum

    // ---- drain: stage strip partials in LDS, then plain coalesced stores
    {
        float* b0 = &cs[SIDX(c0 + 16 * lane)];   // base%16==0 -> SIDX(base+j)=SIDX(base)+j
        *reinterpret_cast<float4*>(b0 + 0)  = ca0;
        *reinterpret_cast<float4*>(b0 + 4)  = ca1;
        *reinterpret_cast<float4*>(b0 + 8)  = ca2;
        *reinterpret_cast<float4*>(b0 + 12) = ca3;
    }
    __syncthreads();
    float* rp = rcp + ((size_t)z * 256 + blockIdx.x) * NN;
    for (int i = 4 * t; i < NN; i += 2048) {             // 4 x float4 per thread
        float4 v4 = *reinterpret_cast<const float4*>(&cs[SIDX(i)]);
        *reinterpret_cast<float4*>(&rp[i]) = v4;
    }
}

// -------------------------------- fold 256 block partials -> v (next iteration)
// grid (64, 1, nb), 512 threads: block owns 128 cols (32 float4); thread
// (tf, tq) float4-sums 16 rows of col-group tf -> LDS -> 32 lanes finalize.
// float4 loads give 512-B coalesced segments per row (round-5 version was 4B/lane).
__global__ __launch_bounds__(512) void sk_reduce(const float* __restrict__ rcp,
                                                 float* __restrict__ v_out) {
    __shared__ float4 sred[16][32];
    const int t = threadIdx.x, tf = t & 31, tq = t >> 5;
    const int z = blockIdx.z;
    const int c0 = blockIdx.x * 128;
    const float* base = rcp + (size_t)z * 256 * NN + c0 + 4 * tf;
    float4 acc = {0, 0, 0, 0};
#pragma unroll 4
    for (int r = tq * 16; r < tq * 16 + 16; r++) {
        float4 p = *reinterpret_cast<const float4*>(base + (size_t)r * NN);
        acc.x += p.x; acc.y += p.y; acc.z += p.z; acc.w += p.w;
    }
    sred[tq][tf] = acc;
    __syncthreads();
    if (t < 32) {
        float4 s = {0, 0, 0, 0};
#pragma unroll
        for (int q = 0; q < 16; q++) {
            float4 p = sred[q][t];
            s.x += p.x; s.y += p.y; s.z += p.z; s.w += p.w;
        }
        float4 g;
        g.x = kMass * __builtin_amdgcn_rcpf(fmaf(s.x, kInvSc, kStab));
        g.y = kMass * __builtin_amdgcn_rcpf(fmaf(s.y, kInvSc, kStab));
        g.z = kMass * __builtin_amdgcn_rcpf(fmaf(s.z, kInvSc, kStab));
        g.w = kMass * __builtin_amdgcn_rcpf(fmaf(s.w, kInvSc, kStab));
        *reinterpret_cast<float4*>(&v_out[(size_t)z * NN + c0 + 4 * t]) = g;
    }
}

// -------------------------------- w[z] = sum u_i K_ij v_j cost_ij, cost = -eps*ln(K)
__global__ __launch_bounds__(256) void sk_wsum(const unsigned char* __restrict__ K8,
                                               const float* __restrict__ v_in,
                                               const float* __restrict__ u,
                                               double* __restrict__ acc_out) {
    __shared__ float vs[10240];
    __shared__ double wred[4];
    const int t = threadIdx.x;
    const int z = blockIdx.z;
    const unsigned char* K = K8 + (size_t)z * NN * NN;
    const float* v = v_in + (size_t)z * NN;
#pragma unroll
    for (int q = 0; q < 8; q++) {
        const int j = 4 * t + 1024 * q;
        *reinterpret_cast<float4*>(&vs[SIDX(j)]) = *reinterpret_cast<const float4*>(v + j);
    }
    __syncthreads();

    const int lane = t & 63, w = t >> 6;
    const int rbase = blockIdx.x * 32 + 8 * w;
    float pr[8] = {};
    const unsigned char* rp = K + (size_t)rbase * NN + 16 * lane;
    for (int s = 0; s < 8; s++) {
        const float* vp = &vs[20 * lane + 1280 * s];
        float vv[16];
#pragma unroll
        for (int g = 0; g < 4; g++) {
            float4 v4 = *reinterpret_cast<const float4*>(vp + 4 * g);
            vv[4 * g] = v4.x; vv[4 * g + 1] = v4.y; vv[4 * g + 2] = v4.z; vv[4 * g + 3] = v4.w;
        }
        const unsigned char* ps = rp + 1024 * s;
#pragma unroll
        for (int r = 0; r < 8; r++) {
            uint4 kk = *reinterpret_cast<const uint4*>(ps + (size_t)r * NN);
            float f[16];
            cvt16(kk, f);
            float a = pr[r];
#pragma unroll
            for (int j = 0; j < 16; j++) {
                // term k*v*ln(k): zero when f==0 since f*v==0
                a = fmaf(f[j] * vv[j], __logf(fmaxf(f[j], 1e-30f) * kInvSc), a);
            }
            pr[r] = a;
        }
    }
    double lacc = 0.0;
#pragma unroll
    for (int r = 0; r < 8; r++)
        lacc += (double)(u[(size_t)z * NN + rbase + r] * pr[r]);
    lacc *= (double)kInvSc;
    for (int off = 32; off > 0; off >>= 1) lacc += __shfl_down(lacc, off);
    if (lane == 0) wred[w] = lacc;
    __syncthreads();
    if (t == 0) {
        double total = -(double)kEps * (wred[0] + wred[1] + wred[2] + wred[3]);
        atomicAdd(&acc_out[z], total);
    }
}

// ------------------------------------------------- combine
__global__ void sk_combine(const double* __restrict__ acc, float* __restrict__ out) {
    if (threadIdx.x == 0)
        out[0] = (float)((acc[0] - 0.5 * acc[1] - 0.5 * acc[2]) / 8192.0);
}

extern "C" void kernel_launch(void* const* d_in, const int* in_sizes, int n_in,
                              void* d_out, int out_size, void* d_ws, size_t ws_size,
                              hipStream_t stream) {
    const float* src = (const float*)d_in[0];
    const float* tgt = (const float*)d_in[1];
    float* out = (float*)d_out;
    char* ws = (char*)d_ws;

    // batched needs: 3 K matrices + 3x256x8192 partials + vectors
    const size_t need3 = 3ull * NN * NN + 3ull * 256 * NN * 4 + 16ull * NN * 4 + 1024;
    const bool batched = ws_size >= need3;
    const int B = batched ? 3 : 1;

    unsigned char* K8 = (unsigned char*)ws;
    float*  rcp  = (float*)(ws + (size_t)B * NN * NN);
    float*  vb   = rcp + (size_t)B * 256 * NN;
    float*  u    = vb + (size_t)B * NN;
    float*  rc0  = u + (size_t)B * NN;
    double* wacc = (double*)(rc0 + (size_t)B * NN);

    hipMemsetAsync(wacc, 0, 3 * sizeof(double), stream);
    const float* pts[3][2] = {{src, tgt}, {src, src}, {tgt, tgt}};

    if (batched) {
        hipMemsetAsync(rc0, 0, 3ull * NN * sizeof(float), stream);
        sk_init_u<<<3 * NN / 256, 256, 0, stream>>>(u);
        for (int i = 0; i < 3; i++)
            sk_build_k<<<dim3(128, 128, 1), 256, 0, stream>>>(pts[i][0], pts[i][1],
                                                              K8 + (size_t)i * NN * NN);
        sk_colsum<<<dim3(8, 64, 3), 256, 0, stream>>>(K8, u, rc0);   // raw K^T 1
        sk_v<<<dim3(32, 1, 3), 256, 0, stream>>>(rc0, vb);           // v_1
        for (int t = 1; t <= 100; t++) {
            sk_iter<<<dim3(256, 1, 3), 512, 0, stream>>>(K8, vb, rcp, u, t == 100 ? 1 : 0);
            if (t < 100)
                sk_reduce<<<dim3(64, 1, 3), 512, 0, stream>>>(rcp, vb);
        }
        // after t=100: u = u_100, vb = v_100
        sk_wsum<<<dim3(256, 1, 3), 256, 0, stream>>>(K8, vb, u, wacc);
    } else {
        for (int tf = 0; tf < 3; tf++) {
            hipMemsetAsync(rc0, 0, 1ull * NN * sizeof(float), stream);
            sk_init_u<<<NN / 256, 256, 0, stream>>>(u);
            sk_build_k<<<dim3(128, 128, 1), 256, 0, stream>>>(pts[tf][0], pts[tf][1], K8);
            sk_colsum<<<dim3(8, 64, 1), 256, 0, stream>>>(K8, u, rc0);
            sk_v<<<dim3(32, 1, 1), 256, 0, stream>>>(rc0, vb);
            for (int t = 1; t <= 100; t++) {
                sk_iter<<<dim3(256, 1, 1), 512, 0, stream>>>(K8, vb, rcp, u, t == 100 ? 1 : 0);
                if (t < 100)
                    sk_reduce<<<dim3(64, 1, 1), 512, 0, stream>>>(rcp, vb);
            }
            sk_wsum<<<dim3(256, 1, 1), 256, 0, stream>>>(K8, vb, u, &wacc[tf]);
        }
    }
    sk_combine<<<1, 64, 0, stream>>>(wacc, out);
}

// Round 7
// 5154.121 us; speedup vs baseline: 9.1554x; 1.1489x over previous
//
#include <hip/hip_runtime.h>

#define NN 8192
#define DD 32
// stagger-padded LDS index: +4 floats of pad per 16 (keeps 16B alignment)
#define SIDX(c) ((c) + 4 * ((c) >> 4))

constexpr float kEps   = 0.1f;
constexpr float kStab  = 1e-8f;
constexpr float kMass  = 1.0f / 8192.0f;     // mu = nu = 1/n
constexpr float kInvSc = 1.0f / 256.0f;      // K stored as fp8 of 256*K
constexpr float kLnSc  = 5.545177444479562f; // ln(256)

typedef float v2f __attribute__((ext_vector_type(2)));

__device__ inline void cvt8x4(unsigned int w, float* out) {
    v2f lo = __builtin_amdgcn_cvt_pk_f32_fp8(w, false);
    v2f hi = __builtin_amdgcn_cvt_pk_f32_fp8(w, true);
    out[0] = lo.x; out[1] = lo.y; out[2] = hi.x; out[3] = hi.y;
}
__device__ inline void cvt16(uint4 kk, float* f) {
    cvt8x4(kk.x, f); cvt8x4(kk.y, f + 4); cvt8x4(kk.z, f + 8); cvt8x4(kk.w, f + 12);
}
__device__ inline unsigned int pack8x4(float a, float b, float c, float d) {
    int v = 0;
    v = __builtin_amdgcn_cvt_pk_fp8_f32(a, b, v, false);
    v = __builtin_amdgcn_cvt_pk_fp8_f32(c, d, v, true);
    return (unsigned int)v;
}
// pack two positive floats to bf16x2 (round-to-nearest-even)
__device__ inline unsigned int bf16pk(float a, float b) {
    unsigned int ua = __float_as_uint(a), ub = __float_as_uint(b);
    ua = (ua + 0x7FFFu + ((ua >> 16) & 1u)) >> 16;
    ub = (ub + 0x7FFFu + ((ub >> 16) & 1u)) >> 16;
    return ua | (ub << 16);
}
// dot of 16 fp8 values against v (by-value float4s -> SROA-friendly)
__device__ inline float dot16v(uint4 kk, float4 a, float4 b, float4 c, float4 d) {
    float f[16];
    cvt16(kk, f);
    float s = 0.f;
    s = fmaf(f[0],  a.x, s); s = fmaf(f[1],  a.y, s);
    s = fmaf(f[2],  a.z, s); s = fmaf(f[3],  a.w, s);
    s = fmaf(f[4],  b.x, s); s = fmaf(f[5],  b.y, s);
    s = fmaf(f[6],  b.z, s); s = fmaf(f[7],  b.w, s);
    s = fmaf(f[8],  c.x, s); s = fmaf(f[9],  c.y, s);
    s = fmaf(f[10], c.z, s); s = fmaf(f[11], c.w, s);
    s = fmaf(f[12], d.x, s); s = fmaf(f[13], d.y, s);
    s = fmaf(f[14], d.z, s); s = fmaf(f[15], d.w, s);
    return s;
}
// col-acc += f8 * ur, accumulators as float4 refs (SROA-friendly)
__device__ inline void axpy16v(uint4 kk, float ur,
                               float4& c0, float4& c1, float4& c2, float4& c3) {
    float f[16];
    cvt16(kk, f);
    c0.x = fmaf(f[0],  ur, c0.x); c0.y = fmaf(f[1],  ur, c0.y);
    c0.z = fmaf(f[2],  ur, c0.z); c0.w = fmaf(f[3],  ur, c0.w);
    c1.x = fmaf(f[4],  ur, c1.x); c1.y = fmaf(f[5],  ur, c1.y);
    c1.z = fmaf(f[6],  ur, c1.z); c1.w = fmaf(f[7],  ur, c1.w);
    c2.x = fmaf(f[8],  ur, c2.x); c2.y = fmaf(f[9],  ur, c2.y);
    c2.z = fmaf(f[10], ur, c2.z); c2.w = fmaf(f[11], ur, c2.w);
    c3.x = fmaf(f[12], ur, c3.x); c3.y = fmaf(f[13], ur, c3.y);
    c3.z = fmaf(f[14], ur, c3.z); c3.w = fmaf(f[15], ur, c3.w);
}

// ---------------------------------------------------------------- init u = 1
__global__ void sk_init_u(float* __restrict__ u) {
    u[blockIdx.x * 256 + threadIdx.x] = 1.0f;
}

// -------------------------------- build K8 = fp8(256*exp(-cost/eps)) for one pair
// 8x8 register tile (128x128 block tile): 4 LDS b128 reads per 64 FMA -- 2x the
// FLOP:LDS ratio of the old 4x4, 4x fewer d-iterations of loop overhead.
// LDS rows SIDX-staggered: strided float4 reads land 2-way on banks (free, m136).
__global__ __launch_bounds__(256) void sk_build_k(const float* __restrict__ X,
                                                  const float* __restrict__ Y,
                                                  unsigned char* __restrict__ K) {
    __shared__ float xs[DD * 160];   // [d][SIDX(row)], row < 128 -> max 155
    __shared__ float ys[DD * 160];
    __shared__ float sx[128], sy[128];
    const int t  = threadIdx.x;
    const int r0 = blockIdx.y * 128, c0 = blockIdx.x * 128;

    for (int idx = t; idx < DD * 128; idx += 256) {
        int d = idx >> 7, row = idx & 127;
        xs[d * 160 + SIDX(row)] = X[(size_t)(r0 + row) * DD + d];
        ys[d * 160 + SIDX(row)] = Y[(size_t)(c0 + row) * DD + d];
    }
    __syncthreads();
    if (t < 128) {
        const int si = SIDX(t);
        float s = 0.f;
        for (int d = 0; d < DD; d++) { float v = xs[d * 160 + si]; s = fmaf(v, v, s); }
        sx[t] = s;
    } else {
        const int q = t - 128, si = SIDX(q);
        float s = 0.f;
        for (int d = 0; d < DD; d++) { float v = ys[d * 160 + si]; s = fmaf(v, v, s); }
        sy[q] = s;
    }
    __syncthreads();

    const int tr = t >> 4, tc = t & 15;
    const int xb = SIDX(8 * tr);     // rows 8tr..8tr+7 are contiguous: SIDX(8tr+4)=SIDX(8tr)+4
    const int yb = SIDX(8 * tc);
    float acc[8][8] = {};
#pragma unroll 4
    for (int d = 0; d < DD; d++) {
        const float* xrow = &xs[d * 160];
        const float* yrow = &ys[d * 160];
        const float4 xa0 = *reinterpret_cast<const float4*>(&xrow[xb]);
        const float4 xa1 = *reinterpret_cast<const float4*>(&xrow[xb + 4]);
        const float4 yb0 = *reinterpret_cast<const float4*>(&yrow[yb]);
        const float4 yb1 = *reinterpret_cast<const float4*>(&yrow[yb + 4]);
        const float xv[8] = {xa0.x, xa0.y, xa0.z, xa0.w, xa1.x, xa1.y, xa1.z, xa1.w};
        const float yv[8] = {yb0.x, yb0.y, yb0.z, yb0.w, yb1.x, yb1.y, yb1.z, yb1.w};
#pragma unroll
        for (int a = 0; a < 8; a++)
#pragma unroll
            for (int b = 0; b < 8; b++) acc[a][b] = fmaf(xv[a], yv[b], acc[a][b]);
    }
#pragma unroll
    for (int a = 0; a < 8; a++) {
        const int r = r0 + 8 * tr + a;
        const float sxa = sx[8 * tr + a];
        float e[8];
#pragma unroll
        for (int b = 0; b < 8; b++) {
            float cost = sxa + sy[8 * tc + b] - 2.0f * acc[a][b];
            cost = fmaxf(cost, 0.0f);
            e[b] = __expf(fmaf(-10.0f, cost, kLnSc));   // 256 * exp(-cost/eps)
        }
        uint2 pk;
        pk.x = pack8x4(e[0], e[1], e[2], e[3]);
        pk.y = pack8x4(e[4], e[5], e[6], e[7]);
        *reinterpret_cast<uint2*>(&K[(size_t)r * NN + c0 + 8 * tc]) = pk;
    }
}

// -------------------------------- initial column sums: rc[z] += K[z]^T u[z] (u = 1)
// one-shot, 64 contenders/address — benign atomic regime (round-0 evidence).
__global__ __launch_bounds__(256) void sk_colsum(const unsigned char* __restrict__ K8,
                                                 const float* __restrict__ u,
                                                 float* __restrict__ rc_out) {
    __shared__ float us[128];
    __shared__ float red[4 * 1280];   // 4 waves x staggered 1024
    const int t = threadIdx.x, lane = t & 63, w = t >> 6;
    const int z = blockIdx.z;
    const int c0 = blockIdx.x * 1024, r0 = blockIdx.y * 128;
    const unsigned char* K = K8 + (size_t)z * NN * NN;
    if (t < 128) us[t] = u[z * NN + r0 + t];
    __syncthreads();

    float acc[16] = {};
    const unsigned char* p = K + (size_t)(r0 + 32 * w) * NN + c0 + 16 * lane;
    for (int i = 0; i < 32; i += 4) {
        uint4 k0 = *reinterpret_cast<const uint4*>(p);
        uint4 k1 = *reinterpret_cast<const uint4*>(p + (size_t)NN);
        uint4 k2 = *reinterpret_cast<const uint4*>(p + (size_t)2 * NN);
        uint4 k3 = *reinterpret_cast<const uint4*>(p + (size_t)3 * NN);
        p += (size_t)4 * NN;
        const float u0 = us[32 * w + i + 0], u1 = us[32 * w + i + 1];
        const float u2 = us[32 * w + i + 2], u3 = us[32 * w + i + 3];
        float f[16];
        cvt16(k0, f);
#pragma unroll
        for (int j = 0; j < 16; j++) acc[j] = fmaf(f[j], u0, acc[j]);
        cvt16(k1, f);
#pragma unroll
        for (int j = 0; j < 16; j++) acc[j] = fmaf(f[j], u1, acc[j]);
        cvt16(k2, f);
#pragma unroll
        for (int j = 0; j < 16; j++) acc[j] = fmaf(f[j], u2, acc[j]);
        cvt16(k3, f);
#pragma unroll
        for (int j = 0; j < 16; j++) acc[j] = fmaf(f[j], u3, acc[j]);
    }
    float* rw = &red[w * 1280 + 20 * lane];   // SIDX(16*lane) = 20*lane
#pragma unroll
    for (int g = 0; g < 4; g++) {
        float4 v = {acc[4 * g + 0], acc[4 * g + 1], acc[4 * g + 2], acc[4 * g + 3]};
        *reinterpret_cast<float4*>(rw + 4 * g) = v;
    }
    __syncthreads();
    for (int c = t; c < 1024; c += 256) {
        const int sc = SIDX(c);
        const float s = red[sc] + red[1280 + sc] + red[2560 + sc] + red[3840 + sc];
        atomicAdd(&rc_out[z * NN + c0 + c], s);
    }
}

// -------------------------------- v[c] = m / (raw[c]/256 + stab)  (once, after colsum)
__global__ void sk_v(const float* __restrict__ rc, float* __restrict__ v) {
    const int i = (blockIdx.z * gridDim.x + blockIdx.x) * 256 + threadIdx.x;
    v[i] = kMass * __builtin_amdgcn_rcpf(fmaf(rc[i], kInvSc, kStab));
}

// -------------------------------- fused iteration, register-resident K, bounded pressure:
// 512 threads = 8 waves. Block owns 32 rows x 8192 cols. Wave w owns col strip
// [1024w, 1024w+1024); lane owns 16 fixed cols (one uint4/row) for ALL rows.
// Group loop is NOT unrolled (pragma unroll 1) with an explicit 1-deep prefetch
// double-buffer, so at most 2 K-groups (32 VGPR) are in flight -- total live
// ~96 VGPR, no scratch spill (round-4 lesson: full unroll hoisted 8 groups of
// loads -> 128-reg cap blown -> 550 MB/dispatch scratch traffic).
// K is read from HBM exactly once; col partials stored non-atomically as BF16
// to rcp[z][bid][8192] (halves the partial stream; 0.01% error after 256-sum,
// two orders below the fp8-K quantization already in K).
__global__ __launch_bounds__(512, 2) void sk_iter(const unsigned char* __restrict__ K8,
                                                  const float* __restrict__ v_in,
                                                  unsigned short* __restrict__ rcp,
                                                  float* __restrict__ u_out,
                                                  int last) {
    __shared__ float cs[10240];        // staggered 8192: colsum drain buffer
    __shared__ float red[8][8][4];     // group x wave x row partial rowsums
    const int t = threadIdx.x, lane = t & 63, w = t >> 6;
    const int z = blockIdx.z;
    const unsigned char* K = K8 + (size_t)z * NN * NN;
    const int rowbase = blockIdx.x * 32;
    const int c0 = 1024 * w;

    // ---- v for this lane's 16 columns, in registers
    float4 va, vb, vc, vd;
    {
        const float* vz = v_in + (size_t)z * NN + c0 + 16 * lane;
        va = reinterpret_cast<const float4*>(vz)[0];
        vb = reinterpret_cast<const float4*>(vz)[1];
        vc = reinterpret_cast<const float4*>(vz)[2];
        vd = reinterpret_cast<const float4*>(vz)[3];
    }

    const unsigned char* kp = K + (size_t)rowbase * NN + c0 + 16 * lane;
    // prefetch group 0 (4 rows x 16 cols of packed fp8)
    uint4 n0 = *reinterpret_cast<const uint4*>(kp);
    uint4 n1 = *reinterpret_cast<const uint4*>(kp + (size_t)NN);
    uint4 n2 = *reinterpret_cast<const uint4*>(kp + (size_t)2 * NN);
    uint4 n3 = *reinterpret_cast<const uint4*>(kp + (size_t)3 * NN);

    float4 ca0 = {0,0,0,0}, ca1 = {0,0,0,0}, ca2 = {0,0,0,0}, ca3 = {0,0,0,0};
#pragma unroll 1
    for (int g = 0; g < 8; g++) {
        const uint4 k0 = n0, k1 = n1, k2 = n2, k3 = n3;
        if (g < 7) {   // issue next group's loads before computing on current
            const unsigned char* np = kp + (size_t)(4 * (g + 1)) * NN;
            n0 = *reinterpret_cast<const uint4*>(np);
            n1 = *reinterpret_cast<const uint4*>(np + (size_t)NN);
            n2 = *reinterpret_cast<const uint4*>(np + (size_t)2 * NN);
            n3 = *reinterpret_cast<const uint4*>(np + (size_t)3 * NN);
        }
        // phase 1: per-lane partial row sums -> wave reduce -> LDS
        float p0 = dot16v(k0, va, vb, vc, vd);
        float p1 = dot16v(k1, va, vb, vc, vd);
        float p2 = dot16v(k2, va, vb, vc, vd);
        float p3 = dot16v(k3, va, vb, vc, vd);
#pragma unroll
        for (int off = 32; off > 0; off >>= 1) {
            p0 += __shfl_down(p0, off);
            p1 += __shfl_down(p1, off);
            p2 += __shfl_down(p2, off);
            p3 += __shfl_down(p3, off);
        }
        if (lane == 0) {
            red[g][w][0] = p0; red[g][w][1] = p1;
            red[g][w][2] = p2; red[g][w][3] = p3;
        }
        __syncthreads();
        // every wave computes u for the 4 rows (identical fp math, no 2nd sync)
        float ug[4];
#pragma unroll
        for (int r = 0; r < 4; r++) {
            float s = 0.f;
#pragma unroll
            for (int ww = 0; ww < 8; ww++) s += red[g][ww][r];
            ug[r] = kMass / (s * kInvSc + kStab);
            if (w == 0 && lane == r) u_out[(size_t)z * NN + rowbase + 4 * g + r] = ug[r];
        }
        // phase 2: re-convert the SAME registers, accumulate column partials
        axpy16v(k0, ug[0], ca0, ca1, ca2, ca3);
        axpy16v(k1, ug[1], ca0, ca1, ca2, ca3);
        axpy16v(k2, ug[2], ca0, ca1, ca2, ca3);
        axpy16v(k3, ug[3], ca0, ca1, ca2, ca3);
    }
    if (last) return;   // uniform: final iteration needs no next colsum

    // ---- drain: stage strip partials in LDS, then bf16-pack coalesced stores
    {
        float* b0 = &cs[SIDX(c0 + 16 * lane)];   // base%16==0 -> SIDX(base+j)=SIDX(base)+j
        *reinterpret_cast<float4*>(b0 + 0)  = ca0;
        *reinterpret_cast<float4*>(b0 + 4)  = ca1;
        *reinterpret_cast<float4*>(b0 + 8)  = ca2;
        *reinterpret_cast<float4*>(b0 + 12) = ca3;
    }
    __syncthreads();
    unsigned short* rp = rcp + ((size_t)z * 256 + blockIdx.x) * NN;
    for (int i = 8 * t; i < NN; i += 4096) {     // 8 cols -> one uint4 of bf16x2
        const int base = SIDX(i);                // i%8==0 -> 8 floats contiguous
        float4 fa = *reinterpret_cast<const float4*>(&cs[base]);
        float4 fb = *reinterpret_cast<const float4*>(&cs[base + 4]);
        uint4 o;
        o.x = bf16pk(fa.x, fa.y); o.y = bf16pk(fa.z, fa.w);
        o.z = bf16pk(fb.x, fb.y); o.w = bf16pk(fb.z, fb.w);
        *reinterpret_cast<uint4*>(&rp[i]) = o;
    }
}

// -------------------------------- fold 256 bf16 block partials -> v (next iteration)
// grid (128, 1, nb), 256 threads: block owns 64 cols. Thread (g=t&7, q=t>>3):
// col-group of 8 bf16 cols (one uint4), 8 partial-rows -> LDS [32][64] -> 64
// lanes fold 32 and emit v. Fully vectorized 16B loads, MLP 8/thread.
__global__ __launch_bounds__(256) void sk_reduce(const unsigned short* __restrict__ rcp,
                                                 float* __restrict__ v_out) {
    __shared__ float red[32 * 64];
    const int t = threadIdx.x, g = t & 7, q = t >> 3;
    const int z = blockIdx.z;
    const int c0 = blockIdx.x * 64;
    const unsigned short* base = rcp + (size_t)z * 256 * NN + c0 + 8 * g;
    float acc[8] = {};
#pragma unroll
    for (int r = 0; r < 8; r++) {
        uint4 hv = *reinterpret_cast<const uint4*>(base + (size_t)(8 * q + r) * NN);
        const unsigned int h[4] = {hv.x, hv.y, hv.z, hv.w};
#pragma unroll
        for (int j = 0; j < 4; j++) {
            acc[2 * j]     += __uint_as_float((h[j] & 0xFFFFu) << 16);
            acc[2 * j + 1] += __uint_as_float(h[j] & 0xFFFF0000u);
        }
    }
    float* rw = &red[q * 64 + g * 8];
    *reinterpret_cast<float4*>(rw)     = {acc[0], acc[1], acc[2], acc[3]};
    *reinterpret_cast<float4*>(rw + 4) = {acc[4], acc[5], acc[6], acc[7]};
    __syncthreads();
    if (t < 64) {
        float s = 0.f;
#pragma unroll 8
        for (int q2 = 0; q2 < 32; q2++) s += red[q2 * 64 + t];
        v_out[(size_t)z * NN + c0 + t] =
            kMass * __builtin_amdgcn_rcpf(fmaf(s, kInvSc, kStab));
    }
}

// -------------------------------- w[z] = sum u_i K_ij v_j cost_ij, cost = -eps*ln(K)
__global__ __launch_bounds__(256) void sk_wsum(const unsigned char* __restrict__ K8,
                                               const float* __restrict__ v_in,
                                               const float* __restrict__ u,
                                               double* __restrict__ acc_out) {
    __shared__ float vs[10240];
    __shared__ double wred[4];
    const int t = threadIdx.x;
    const int z = blockIdx.z;
    const unsigned char* K = K8 + (size_t)z * NN * NN;
    const float* v = v_in + (size_t)z * NN;
#pragma unroll
    for (int q = 0; q < 8; q++) {
        const int j = 4 * t + 1024 * q;
        *reinterpret_cast<float4*>(&vs[SIDX(j)]) = *reinterpret_cast<const float4*>(v + j);
    }
    __syncthreads();

    const int lane = t & 63, w = t >> 6;
    const int rbase = blockIdx.x * 32 + 8 * w;
    float pr[8] = {};
    const unsigned char* rp = K + (size_t)rbase * NN + 16 * lane;
    for (int s = 0; s < 8; s++) {
        const float* vp = &vs[20 * lane + 1280 * s];
        float vv[16];
#pragma unroll
        for (int g = 0; g < 4; g++) {
            float4 v4 = *reinterpret_cast<const float4*>(vp + 4 * g);
            vv[4 * g] = v4.x; vv[4 * g + 1] = v4.y; vv[4 * g + 2] = v4.z; vv[4 * g + 3] = v4.w;
        }
        const unsigned char* ps = rp + 1024 * s;
#pragma unroll
        for (int r = 0; r < 8; r++) {
            uint4 kk = *reinterpret_cast<const uint4*>(ps + (size_t)r * NN);
            float f[16];
            cvt16(kk, f);
            float a = pr[r];
#pragma unroll
            for (int j = 0; j < 16; j++) {
                // term k*v*ln(k): zero when f==0 since f*v==0
                a = fmaf(f[j] * vv[j], __logf(fmaxf(f[j], 1e-30f) * kInvSc), a);
            }
            pr[r] = a;
        }
    }
    double lacc = 0.0;
#pragma unroll
    for (int r = 0; r < 8; r++)
        lacc += (double)(u[(size_t)z * NN + rbase + r] * pr[r]);
    lacc *= (double)kInvSc;
    for (int off = 32; off > 0; off >>= 1) lacc += __shfl_down(lacc, off);
    if (lane == 0) wred[w] = lacc;
    __syncthreads();
    if (t == 0) {
        double total = -(double)kEps * (wred[0] + wred[1] + wred[2] + wred[3]);
        atomicAdd(&acc_out[z], total);
    }
}

// ------------------------------------------------- combine
__global__ void sk_combine(const double* __restrict__ acc, float* __restrict__ out) {
    if (threadIdx.x == 0)
        out[0] = (float)((acc[0] - 0.5 * acc[1] - 0.5 * acc[2]) / 8192.0);
}

extern "C" void kernel_launch(void* const* d_in, const int* in_sizes, int n_in,
                              void* d_out, int out_size, void* d_ws, size_t ws_size,
                              hipStream_t stream) {
    const float* src = (const float*)d_in[0];
    const float* tgt = (const float*)d_in[1];
    float* out = (float*)d_out;
    char* ws = (char*)d_ws;

    // batched needs: 3 K matrices + 3x256x8192 bf16 partials + vectors
    const size_t need3 = 3ull * NN * NN + 3ull * 256 * NN * 2 + 16ull * NN * 4 + 1024;
    const bool batched = ws_size >= need3;
    const int B = batched ? 3 : 1;

    unsigned char*  K8  = (unsigned char*)ws;
    unsigned short* rcp = (unsigned short*)(ws + (size_t)B * NN * NN);
    float*  vb   = (float*)((char*)rcp + (size_t)B * 256 * NN * 2);
    float*  u    = vb + (size_t)B * NN;
    float*  rc0  = u + (size_t)B * NN;
    double* wacc = (double*)(rc0 + (size_t)B * NN);

    hipMemsetAsync(wacc, 0, 3 * sizeof(double), stream);
    const float* pts[3][2] = {{src, tgt}, {src, src}, {tgt, tgt}};

    if (batched) {
        hipMemsetAsync(rc0, 0, 3ull * NN * sizeof(float), stream);
        sk_init_u<<<3 * NN / 256, 256, 0, stream>>>(u);
        for (int i = 0; i < 3; i++)
            sk_build_k<<<dim3(64, 64, 1), 256, 0, stream>>>(pts[i][0], pts[i][1],
                                                            K8 + (size_t)i * NN * NN);
        sk_colsum<<<dim3(8, 64, 3), 256, 0, stream>>>(K8, u, rc0);   // raw K^T 1
        sk_v<<<dim3(32, 1, 3), 256, 0, stream>>>(rc0, vb);           // v_1
        for (int t = 1; t <= 100; t++) {
            sk_iter<<<dim3(256, 1, 3), 512, 0, stream>>>(K8, vb, rcp, u, t == 100 ? 1 : 0);
            if (t < 100)
                sk_reduce<<<dim3(128, 1, 3), 256, 0, stream>>>(rcp, vb);
        }
        // after t=100: u = u_100, vb = v_100
        sk_wsum<<<dim3(256, 1, 3), 256, 0, stream>>>(K8, vb, u, wacc);
    } else {
        for (int tf = 0; tf < 3; tf++) {
            hipMemsetAsync(rc0, 0, 1ull * NN * sizeof(float), stream);
            sk_init_u<<<NN / 256, 256, 0, stream>>>(u);
            sk_build_k<<<dim3(64, 64, 1), 256, 0, stream>>>(pts[tf][0], pts[tf][1], K8);
            sk_colsum<<<dim3(8, 64, 1), 256, 0, stream>>>(K8, u, rc0);
            sk_v<<<dim3(32, 1, 1), 256, 0, stream>>>(rc0, vb);
            for (int t = 1; t <= 100; t++) {
                sk_iter<<<dim3(256, 1, 1), 512, 0, stream>>>(K8, vb, rcp, u, t == 100 ? 1 : 0);
                if (t < 100)
                    sk_reduce<<<dim3(128, 1, 1), 256, 0, stream>>>(rcp, vb);
            }
            sk_wsum<<<dim3(256, 1, 1), 256, 0, stream>>>(K8, vb, u, &wacc[tf]);
        }
    }
    sk_combine<<<1, 64, 0, stream>>>(wacc, out);
}

// Round 8
// 4773.919 us; speedup vs baseline: 9.8845x; 1.0796x over previous
//
#include <hip/hip_runtime.h>

#define NN 8192
#define DD 32
// stagger-padded LDS index: +4 floats of pad per 16 (keeps 16B alignment)
#define SIDX(c) ((c) + 4 * ((c) >> 4))

constexpr float kEps   = 0.1f;
constexpr float kStab  = 1e-8f;
constexpr float kMass  = 1.0f / 8192.0f;     // mu = nu = 1/n
constexpr float kInvSc = 1.0f / 256.0f;      // K stored as fp8 of 256*K
constexpr float kLnSc  = 5.545177444479562f; // ln(256)

typedef float v2f __attribute__((ext_vector_type(2)));

__device__ inline void cvt8x4(unsigned int w, float* out) {
    v2f lo = __builtin_amdgcn_cvt_pk_f32_fp8(w, false);
    v2f hi = __builtin_amdgcn_cvt_pk_f32_fp8(w, true);
    out[0] = lo.x; out[1] = lo.y; out[2] = hi.x; out[3] = hi.y;
}
__device__ inline void cvt16(uint4 kk, float* f) {
    cvt8x4(kk.x, f); cvt8x4(kk.y, f + 4); cvt8x4(kk.z, f + 8); cvt8x4(kk.w, f + 12);
}
// paired (v2f) conversion: 16 fp8 -> 8 float2, stays in packed-math form
__device__ inline void cvt16v2(uint4 kk, v2f* f) {
    f[0] = __builtin_amdgcn_cvt_pk_f32_fp8(kk.x, false);
    f[1] = __builtin_amdgcn_cvt_pk_f32_fp8(kk.x, true);
    f[2] = __builtin_amdgcn_cvt_pk_f32_fp8(kk.y, false);
    f[3] = __builtin_amdgcn_cvt_pk_f32_fp8(kk.y, true);
    f[4] = __builtin_amdgcn_cvt_pk_f32_fp8(kk.z, false);
    f[5] = __builtin_amdgcn_cvt_pk_f32_fp8(kk.z, true);
    f[6] = __builtin_amdgcn_cvt_pk_f32_fp8(kk.w, false);
    f[7] = __builtin_amdgcn_cvt_pk_f32_fp8(kk.w, true);
}
__device__ inline unsigned int pack8x4(float a, float b, float c, float d) {
    int v = 0;
    v = __builtin_amdgcn_cvt_pk_fp8_f32(a, b, v, false);
    v = __builtin_amdgcn_cvt_pk_fp8_f32(c, d, v, true);
    return (unsigned int)v;
}
// pack two positive floats to bf16x2 (round-to-nearest-even)
__device__ inline unsigned int bf16pk(float a, float b) {
    unsigned int ua = __float_as_uint(a), ub = __float_as_uint(b);
    ua = (ua + 0x7FFFu + ((ua >> 16) & 1u)) >> 16;
    ub = (ub + 0x7FFFu + ((ub >> 16) & 1u)) >> 16;
    return ua | (ub << 16);
}
// packed dot: 16 fp8 x 8 v2f -> scalar (8 v_pk_fma_f32 instead of 16 v_fma_f32)
__device__ inline float dot16p(uint4 kk, const v2f* vv) {
    v2f f[8];
    cvt16v2(kk, f);
    v2f acc = {0.f, 0.f};
#pragma unroll
    for (int i = 0; i < 8; i++) acc = __builtin_elementwise_fma(f[i], vv[i], acc);
    return acc.x + acc.y;
}
// packed axpy: ca[8] (v2f) += fp8x16 * ur
__device__ inline void axpy16p(uint4 kk, float ur, v2f* ca) {
    v2f f[8];
    cvt16v2(kk, f);
    const v2f u2 = {ur, ur};
#pragma unroll
    for (int i = 0; i < 8; i++) ca[i] = __builtin_elementwise_fma(f[i], u2, ca[i]);
}

// ---------------------------------------------------------------- init u = 1
__global__ void sk_init_u(float* __restrict__ u) {
    u[blockIdx.x * 256 + threadIdx.x] = 1.0f;
}

// -------------------------------- build K8 = fp8(256*exp(-cost/eps)) for one pair
// 8x8 register tile (128x128 block tile); __expf; SIDX-staggered LDS.
__global__ __launch_bounds__(256) void sk_build_k(const float* __restrict__ X,
                                                  const float* __restrict__ Y,
                                                  unsigned char* __restrict__ K) {
    __shared__ float xs[DD * 160];   // [d][SIDX(row)], row < 128 -> max 155
    __shared__ float ys[DD * 160];
    __shared__ float sx[128], sy[128];
    const int t  = threadIdx.x;
    const int r0 = blockIdx.y * 128, c0 = blockIdx.x * 128;

    for (int idx = t; idx < DD * 128; idx += 256) {
        int d = idx >> 7, row = idx & 127;
        xs[d * 160 + SIDX(row)] = X[(size_t)(r0 + row) * DD + d];
        ys[d * 160 + SIDX(row)] = Y[(size_t)(c0 + row) * DD + d];
    }
    __syncthreads();
    if (t < 128) {
        const int si = SIDX(t);
        float s = 0.f;
        for (int d = 0; d < DD; d++) { float v = xs[d * 160 + si]; s = fmaf(v, v, s); }
        sx[t] = s;
    } else {
        const int q = t - 128, si = SIDX(q);
        float s = 0.f;
        for (int d = 0; d < DD; d++) { float v = ys[d * 160 + si]; s = fmaf(v, v, s); }
        sy[q] = s;
    }
    __syncthreads();

    const int tr = t >> 4, tc = t & 15;
    const int xb = SIDX(8 * tr);     // rows 8tr..8tr+7 contiguous in SIDX space
    const int yb = SIDX(8 * tc);
    float acc[8][8] = {};
#pragma unroll 4
    for (int d = 0; d < DD; d++) {
        const float* xrow = &xs[d * 160];
        const float* yrow = &ys[d * 160];
        const float4 xa0 = *reinterpret_cast<const float4*>(&xrow[xb]);
        const float4 xa1 = *reinterpret_cast<const float4*>(&xrow[xb + 4]);
        const float4 yb0 = *reinterpret_cast<const float4*>(&yrow[yb]);
        const float4 yb1 = *reinterpret_cast<const float4*>(&yrow[yb + 4]);
        const float xv[8] = {xa0.x, xa0.y, xa0.z, xa0.w, xa1.x, xa1.y, xa1.z, xa1.w};
        const float yv[8] = {yb0.x, yb0.y, yb0.z, yb0.w, yb1.x, yb1.y, yb1.z, yb1.w};
#pragma unroll
        for (int a = 0; a < 8; a++)
#pragma unroll
            for (int b = 0; b < 8; b++) acc[a][b] = fmaf(xv[a], yv[b], acc[a][b]);
    }
#pragma unroll
    for (int a = 0; a < 8; a++) {
        const int r = r0 + 8 * tr + a;
        const float sxa = sx[8 * tr + a];
        float e[8];
#pragma unroll
        for (int b = 0; b < 8; b++) {
            float cost = sxa + sy[8 * tc + b] - 2.0f * acc[a][b];
            cost = fmaxf(cost, 0.0f);
            e[b] = __expf(fmaf(-10.0f, cost, kLnSc));   // 256 * exp(-cost/eps)
        }
        uint2 pk;
        pk.x = pack8x4(e[0], e[1], e[2], e[3]);
        pk.y = pack8x4(e[4], e[5], e[6], e[7]);
        *reinterpret_cast<uint2*>(&K[(size_t)r * NN + c0 + 8 * tc]) = pk;
    }
}

// -------------------------------- initial column sums: rc[z] += K[z]^T u[z] (u = 1)
__global__ __launch_bounds__(256) void sk_colsum(const unsigned char* __restrict__ K8,
                                                 const float* __restrict__ u,
                                                 float* __restrict__ rc_out) {
    __shared__ float us[128];
    __shared__ float red[4 * 1280];   // 4 waves x staggered 1024
    const int t = threadIdx.x, lane = t & 63, w = t >> 6;
    const int z = blockIdx.z;
    const int c0 = blockIdx.x * 1024, r0 = blockIdx.y * 128;
    const unsigned char* K = K8 + (size_t)z * NN * NN;
    if (t < 128) us[t] = u[z * NN + r0 + t];
    __syncthreads();

    float acc[16] = {};
    const unsigned char* p = K + (size_t)(r0 + 32 * w) * NN + c0 + 16 * lane;
    for (int i = 0; i < 32; i += 4) {
        uint4 k0 = *reinterpret_cast<const uint4*>(p);
        uint4 k1 = *reinterpret_cast<const uint4*>(p + (size_t)NN);
        uint4 k2 = *reinterpret_cast<const uint4*>(p + (size_t)2 * NN);
        uint4 k3 = *reinterpret_cast<const uint4*>(p + (size_t)3 * NN);
        p += (size_t)4 * NN;
        const float u0 = us[32 * w + i + 0], u1 = us[32 * w + i + 1];
        const float u2 = us[32 * w + i + 2], u3 = us[32 * w + i + 3];
        float f[16];
        cvt16(k0, f);
#pragma unroll
        for (int j = 0; j < 16; j++) acc[j] = fmaf(f[j], u0, acc[j]);
        cvt16(k1, f);
#pragma unroll
        for (int j = 0; j < 16; j++) acc[j] = fmaf(f[j], u1, acc[j]);
        cvt16(k2, f);
#pragma unroll
        for (int j = 0; j < 16; j++) acc[j] = fmaf(f[j], u2, acc[j]);
        cvt16(k3, f);
#pragma unroll
        for (int j = 0; j < 16; j++) acc[j] = fmaf(f[j], u3, acc[j]);
    }
    float* rw = &red[w * 1280 + 20 * lane];   // SIDX(16*lane) = 20*lane
#pragma unroll
    for (int g = 0; g < 4; g++) {
        float4 v = {acc[4 * g + 0], acc[4 * g + 1], acc[4 * g + 2], acc[4 * g + 3]};
        *reinterpret_cast<float4*>(rw + 4 * g) = v;
    }
    __syncthreads();
    for (int c = t; c < 1024; c += 256) {
        const int sc = SIDX(c);
        const float s = red[sc] + red[1280 + sc] + red[2560 + sc] + red[3840 + sc];
        atomicAdd(&rc_out[z * NN + c0 + c], s);
    }
}

// -------------------------------- v[c] = m / (raw[c]/256 + stab)  (once, after colsum)
__global__ void sk_v(const float* __restrict__ rc, float* __restrict__ v) {
    const int i = (blockIdx.z * gridDim.x + blockIdx.x) * 256 + threadIdx.x;
    v[i] = kMass * __builtin_amdgcn_rcpf(fmaf(rc[i], kInvSc, kStab));
}

// -------------------------------- fused iteration, register-resident K, packed math:
// 512 threads = 8 waves; block owns 32 rows x 8192 cols; lane owns 16 fixed cols.
// Round-7 PMC/arith: iter was VALU-bound (~38 us floor at 48 VALU ops / 16 bytes).
// v2f + v_pk_fma_f32 cuts dot+axpy from 32 to 16 FMA insts per 16 bytes.
// Group loop unroll 1 + explicit 1-deep prefetch (round-4 spill lesson).
__global__ __launch_bounds__(512, 2) void sk_iter(const unsigned char* __restrict__ K8,
                                                  const float* __restrict__ v_in,
                                                  unsigned short* __restrict__ rcp,
                                                  float* __restrict__ u_out,
                                                  int last) {
    __shared__ float cs[10240];        // staggered 8192: colsum drain buffer
    __shared__ float red[8][8][4];     // group x wave x row partial rowsums
    const int t = threadIdx.x, lane = t & 63, w = t >> 6;
    const int z = blockIdx.z;
    const unsigned char* K = K8 + (size_t)z * NN * NN;
    const int rowbase = blockIdx.x * 32;
    const int c0 = 1024 * w;

    // ---- v for this lane's 16 columns, as 8 packed pairs in registers
    v2f vv[8];
    {
        const float* vz = v_in + (size_t)z * NN + c0 + 16 * lane;
        const float4 q0 = reinterpret_cast<const float4*>(vz)[0];
        const float4 q1 = reinterpret_cast<const float4*>(vz)[1];
        const float4 q2 = reinterpret_cast<const float4*>(vz)[2];
        const float4 q3 = reinterpret_cast<const float4*>(vz)[3];
        vv[0] = {q0.x, q0.y}; vv[1] = {q0.z, q0.w};
        vv[2] = {q1.x, q1.y}; vv[3] = {q1.z, q1.w};
        vv[4] = {q2.x, q2.y}; vv[5] = {q2.z, q2.w};
        vv[6] = {q3.x, q3.y}; vv[7] = {q3.z, q3.w};
    }

    const unsigned char* kp = K + (size_t)rowbase * NN + c0 + 16 * lane;
    // prefetch group 0 (4 rows x 16 cols of packed fp8)
    uint4 n0 = *reinterpret_cast<const uint4*>(kp);
    uint4 n1 = *reinterpret_cast<const uint4*>(kp + (size_t)NN);
    uint4 n2 = *reinterpret_cast<const uint4*>(kp + (size_t)2 * NN);
    uint4 n3 = *reinterpret_cast<const uint4*>(kp + (size_t)3 * NN);

    v2f ca[8] = {{0,0},{0,0},{0,0},{0,0},{0,0},{0,0},{0,0},{0,0}};
#pragma unroll 1
    for (int g = 0; g < 8; g++) {
        const uint4 k0 = n0, k1 = n1, k2 = n2, k3 = n3;
        if (g < 7) {   // issue next group's loads before computing on current
            const unsigned char* np = kp + (size_t)(4 * (g + 1)) * NN;
            n0 = *reinterpret_cast<const uint4*>(np);
            n1 = *reinterpret_cast<const uint4*>(np + (size_t)NN);
            n2 = *reinterpret_cast<const uint4*>(np + (size_t)2 * NN);
            n3 = *reinterpret_cast<const uint4*>(np + (size_t)3 * NN);
        }
        // phase 1: per-lane partial row sums -> wave reduce -> LDS
        float p0 = dot16p(k0, vv);
        float p1 = dot16p(k1, vv);
        float p2 = dot16p(k2, vv);
        float p3 = dot16p(k3, vv);
#pragma unroll
        for (int off = 32; off > 0; off >>= 1) {
            p0 += __shfl_down(p0, off);
            p1 += __shfl_down(p1, off);
            p2 += __shfl_down(p2, off);
            p3 += __shfl_down(p3, off);
        }
        if (lane == 0) {
            red[g][w][0] = p0; red[g][w][1] = p1;
            red[g][w][2] = p2; red[g][w][3] = p3;
        }
        __syncthreads();
        // every wave computes u for the 4 rows (identical fp math, no 2nd sync)
        float ug[4];
#pragma unroll
        for (int r = 0; r < 4; r++) {
            float s = 0.f;
#pragma unroll
            for (int ww = 0; ww < 8; ww++) s += red[g][ww][r];
            ug[r] = kMass / (s * kInvSc + kStab);
            if (w == 0 && lane == r) u_out[(size_t)z * NN + rowbase + 4 * g + r] = ug[r];
        }
        // phase 2: re-convert the SAME registers, accumulate column partials
        axpy16p(k0, ug[0], ca);
        axpy16p(k1, ug[1], ca);
        axpy16p(k2, ug[2], ca);
        axpy16p(k3, ug[3], ca);
    }
    if (last) return;   // uniform: final iteration needs no next colsum

    // ---- drain: stage strip partials in LDS, then bf16-pack coalesced stores
    {
        float* b0 = &cs[SIDX(c0 + 16 * lane)];   // base%16==0 -> SIDX(base+j)=SIDX(base)+j
        float4 o0 = {ca[0].x, ca[0].y, ca[1].x, ca[1].y};
        float4 o1 = {ca[2].x, ca[2].y, ca[3].x, ca[3].y};
        float4 o2 = {ca[4].x, ca[4].y, ca[5].x, ca[5].y};
        float4 o3 = {ca[6].x, ca[6].y, ca[7].x, ca[7].y};
        *reinterpret_cast<float4*>(b0 + 0)  = o0;
        *reinterpret_cast<float4*>(b0 + 4)  = o1;
        *reinterpret_cast<float4*>(b0 + 8)  = o2;
        *reinterpret_cast<float4*>(b0 + 12) = o3;
    }
    __syncthreads();
    unsigned short* rp = rcp + ((size_t)z * 256 + blockIdx.x) * NN;
    for (int i = 8 * t; i < NN; i += 4096) {     // 8 cols -> one uint4 of bf16x2
        const int base = SIDX(i);                // i%8==0 -> 8 floats contiguous
        float4 fa = *reinterpret_cast<const float4*>(&cs[base]);
        float4 fb = *reinterpret_cast<const float4*>(&cs[base + 4]);
        uint4 o;
        o.x = bf16pk(fa.x, fa.y); o.y = bf16pk(fa.z, fa.w);
        o.z = bf16pk(fb.x, fb.y); o.w = bf16pk(fb.z, fb.w);
        *reinterpret_cast<uint4*>(&rp[i]) = o;
    }
}

// -------------------------------- fold 256 bf16 block partials -> v (next iteration)
__global__ __launch_bounds__(256) void sk_reduce(const unsigned short* __restrict__ rcp,
                                                 float* __restrict__ v_out) {
    __shared__ float red[32 * 64];
    const int t = threadIdx.x, g = t & 7, q = t >> 3;
    const int z = blockIdx.z;
    const int c0 = blockIdx.x * 64;
    const unsigned short* base = rcp + (size_t)z * 256 * NN + c0 + 8 * g;
    float acc[8] = {};
#pragma unroll
    for (int r = 0; r < 8; r++) {
        uint4 hv = *reinterpret_cast<const uint4*>(base + (size_t)(8 * q + r) * NN);
        const unsigned int h[4] = {hv.x, hv.y, hv.z, hv.w};
#pragma unroll
        for (int j = 0; j < 4; j++) {
            acc[2 * j]     += __uint_as_float((h[j] & 0xFFFFu) << 16);
            acc[2 * j + 1] += __uint_as_float(h[j] & 0xFFFF0000u);
        }
    }
    float* rw = &red[q * 64 + g * 8];
    *reinterpret_cast<float4*>(rw)     = {acc[0], acc[1], acc[2], acc[3]};
    *reinterpret_cast<float4*>(rw + 4) = {acc[4], acc[5], acc[6], acc[7]};
    __syncthreads();
    if (t < 64) {
        float s = 0.f;
#pragma unroll 8
        for (int q2 = 0; q2 < 32; q2++) s += red[q2 * 64 + t];
        v_out[(size_t)z * NN + c0 + t] =
            kMass * __builtin_amdgcn_rcpf(fmaf(s, kInvSc, kStab));
    }
}

// -------------------------------- w[z] = sum u_i K_ij v_j cost_ij, cost = -eps*ln(K)
// Round-7 PMC: 84-87% VALUBusy, log-chain-bound. K bytes take 256 values -> LUT
// g[b] = f * ln(f/256) in LDS; per-element work becomes extract+ds_read+fma.
__global__ __launch_bounds__(256) void sk_wsum(const unsigned char* __restrict__ K8,
                                               const float* __restrict__ v_in,
                                               const float* __restrict__ u,
                                               double* __restrict__ acc_out) {
    __shared__ float vs[10240];
    __shared__ float glut[256];
    __shared__ double wred[4];
    const int t = threadIdx.x;
    const int z = blockIdx.z;
    const unsigned char* K = K8 + (size_t)z * NN * NN;
    const float* v = v_in + (size_t)z * NN;
    {
        // LUT: byte b -> f*ln(f/256), f = fp8_decode(b). NaN/neg/zero -> 0
        v2f d = __builtin_amdgcn_cvt_pk_f32_fp8((unsigned int)t, false);
        const float f = d.x;
        glut[t] = (f > 0.f) ? f * __logf(f * kInvSc) : 0.f;
    }
#pragma unroll
    for (int q = 0; q < 8; q++) {
        const int j = 4 * t + 1024 * q;
        *reinterpret_cast<float4*>(&vs[SIDX(j)]) = *reinterpret_cast<const float4*>(v + j);
    }
    __syncthreads();

    const int lane = t & 63, w = t >> 6;
    const int rbase = blockIdx.x * 32 + 8 * w;
    float pr[8] = {};
    const unsigned char* rp = K + (size_t)rbase * NN + 16 * lane;
    for (int s = 0; s < 8; s++) {
        const float* vp = &vs[20 * lane + 1280 * s];
        float vv[16];
#pragma unroll
        for (int g = 0; g < 4; g++) {
            float4 v4 = *reinterpret_cast<const float4*>(vp + 4 * g);
            vv[4 * g] = v4.x; vv[4 * g + 1] = v4.y; vv[4 * g + 2] = v4.z; vv[4 * g + 3] = v4.w;
        }
        const unsigned char* ps = rp + 1024 * s;
#pragma unroll
        for (int r = 0; r < 8; r++) {
            uint4 kk = *reinterpret_cast<const uint4*>(ps + (size_t)r * NN);
            float a = pr[r];
            const unsigned int wrds[4] = {kk.x, kk.y, kk.z, kk.w};
#pragma unroll
            for (int j = 0; j < 4; j++) {
                const unsigned int wv = wrds[j];
                a = fmaf(vv[4 * j + 0], glut[wv & 255u], a);
                a = fmaf(vv[4 * j + 1], glut[(wv >> 8) & 255u], a);
                a = fmaf(vv[4 * j + 2], glut[(wv >> 16) & 255u], a);
                a = fmaf(vv[4 * j + 3], glut[wv >> 24], a);
            }
            pr[r] = a;
        }
    }
    double lacc = 0.0;
#pragma unroll
    for (int r = 0; r < 8; r++)
        lacc += (double)(u[(size_t)z * NN + rbase + r] * pr[r]);
    lacc *= (double)kInvSc;
    for (int off = 32; off > 0; off >>= 1) lacc += __shfl_down(lacc, off);
    if (lane == 0) wred[w] = lacc;
    __syncthreads();
    if (t == 0) {
        double total = -(double)kEps * (wred[0] + wred[1] + wred[2] + wred[3]);
        atomicAdd(&acc_out[z], total);
    }
}

// ------------------------------------------------- combine
__global__ void sk_combine(const double* __restrict__ acc, float* __restrict__ out) {
    if (threadIdx.x == 0)
        out[0] = (float)((acc[0] - 0.5 * acc[1] - 0.5 * acc[2]) / 8192.0);
}

extern "C" void kernel_launch(void* const* d_in, const int* in_sizes, int n_in,
                              void* d_out, int out_size, void* d_ws, size_t ws_size,
                              hipStream_t stream) {
    const float* src = (const float*)d_in[0];
    const float* tgt = (const float*)d_in[1];
    float* out = (float*)d_out;
    char* ws = (char*)d_ws;

    // batched needs: 3 K matrices + 3x256x8192 bf16 partials + vectors
    const size_t need3 = 3ull * NN * NN + 3ull * 256 * NN * 2 + 16ull * NN * 4 + 1024;
    const bool batched = ws_size >= need3;
    const int B = batched ? 3 : 1;

    unsigned char*  K8  = (unsigned char*)ws;
    unsigned short* rcp = (unsigned short*)(ws + (size_t)B * NN * NN);
    float*  vb   = (float*)((char*)rcp + (size_t)B * 256 * NN * 2);
    float*  u    = vb + (size_t)B * NN;
    float*  rc0  = u + (size_t)B * NN;
    double* wacc = (double*)(rc0 + (size_t)B * NN);

    hipMemsetAsync(wacc, 0, 3 * sizeof(double), stream);
    const float* pts[3][2] = {{src, tgt}, {src, src}, {tgt, tgt}};

    if (batched) {
        hipMemsetAsync(rc0, 0, 3ull * NN * sizeof(float), stream);
        sk_init_u<<<3 * NN / 256, 256, 0, stream>>>(u);
        for (int i = 0; i < 3; i++)
            sk_build_k<<<dim3(64, 64, 1), 256, 0, stream>>>(pts[i][0], pts[i][1],
                                                            K8 + (size_t)i * NN * NN);
        sk_colsum<<<dim3(8, 64, 3), 256, 0, stream>>>(K8, u, rc0);   // raw K^T 1
        sk_v<<<dim3(32, 1, 3), 256, 0, stream>>>(rc0, vb);           // v_1
        for (int t = 1; t <= 100; t++) {
            sk_iter<<<dim3(256, 1, 3), 512, 0, stream>>>(K8, vb, rcp, u, t == 100 ? 1 : 0);
            if (t < 100)
                sk_reduce<<<dim3(128, 1, 3), 256, 0, stream>>>(rcp, vb);
        }
        // after t=100: u = u_100, vb = v_100
        sk_wsum<<<dim3(256, 1, 3), 256, 0, stream>>>(K8, vb, u, wacc);
    } else {
        for (int tf = 0; tf < 3; tf++) {
            hipMemsetAsync(rc0, 0, 1ull * NN * sizeof(float), stream);
            sk_init_u<<<NN / 256, 256, 0, stream>>>(u);
            sk_build_k<<<dim3(64, 64, 1), 256, 0, stream>>>(pts[tf][0], pts[tf][1], K8);
            sk_colsum<<<dim3(8, 64, 1), 256, 0, stream>>>(K8, u, rc0);
            sk_v<<<dim3(32, 1, 1), 256, 0, stream>>>(rc0, vb);
            for (int t = 1; t <= 100; t++) {
                sk_iter<<<dim3(256, 1, 1), 512, 0, stream>>>(K8, vb, rcp, u, t == 100 ? 1 : 0);
                if (t < 100)
                    sk_reduce<<<dim3(128, 1, 1), 256, 0, stream>>>(rcp, vb);
            }
            sk_wsum<<<dim3(256, 1, 1), 256, 0, stream>>>(K8, vb, u, &wacc[tf]);
        }
    }
    sk_combine<<<1, 64, 0, stream>>>(wacc, out);
}